// Round 6
// baseline (4227.628 us; speedup 1.0000x reference)
//
#include <hip/hip_runtime.h>

#define T_STEPS 512
#define BATCH   256
#define DIN     256
#define DHID    256
#define NWG     64       // each WG: 2 sets x 2 batch rows
#define NTHREADS 256     // 4 waves, wave = gate

typedef short bf16_t;
typedef __attribute__((ext_vector_type(4))) short short4v;
typedef __attribute__((ext_vector_type(8))) short short8;
typedef __attribute__((ext_vector_type(4))) float f32x4;
typedef unsigned int uint;
typedef unsigned short ushort;

// ---- REC LDS layout (bytes) ----
#define OFF_WL  0
#define SZ_WL   (4 * 16 * 2 * 64 * 16)          // 131072: kt6,7 frags
#define OFF_AP  (OFF_WL + SZ_WL)                // set P: 2 rows x 512B
#define SZ_A    1024
#define OFF_AQ  (OFF_AP + SZ_A)
#define OFF_TH  (OFF_AQ + SZ_A)                 // raw theta f32 [8][260]
#define THSTRF  260
#define SZ_TH   (8 * THSTRF * 4)                // 8320
#define OFF_ACT (OFF_TH + SZ_TH)                // act bf16 [8][264]
#define ACTSTR  264
#define SZ_ACT  (8 * ACTSTR * 2)                // 4224
#define LDS_REC (OFF_ACT + SZ_ACT)              // 145664

// ---- workspace layout (bytes) ----
#define WS_WHP   0u                        // 512 KB Wh packed (B-frag order)
#define WS_WXP   (512u << 10)              // 512 KB Wx packed
#define WS_BIAS  (1u << 20)                // 4 KB
#define WS_TMP   ((1u << 20) + 4096u)      // 16 B
#define WS_HG    ((1u << 20) + 8192u)      // 128 KB h state bf16 [256][256]
#define WS_CG    ((1u << 20) + 8192u + 131072u)  // 256 KB c state f32
#define WS_THX   (2u << 20)                // CH*512 KB theta_x chunk

__device__ inline short f2bf(float f) {
  union { float f; uint u; } v; v.f = f;
  uint r = (v.u + 0x7FFFu + ((v.u >> 16) & 1u)) >> 16;
  return (short)r;
}
__device__ inline float bf2fu(ushort s) {
  union { float f; uint u; } v; v.u = ((uint)s) << 16;
  return v.f;
}
__device__ inline float u2f(uint u) {
  union { float f; uint u; } v; v.u = u; return v.f;
}
__device__ inline float frcp(float x) { return __builtin_amdgcn_rcpf(x); }
__device__ inline float fast_sigmoid(float x) { return frcp(1.f + __expf(-x)); }
__device__ inline float fast_tanh(float x) {
  float ax = fabsf(x);
  float e = __expf(2.f * ax);              // inf-safe
  float r = 1.f - 2.f * frcp(e + 1.f);
  return copysignf(r, x);
}

// asm MFMA with B operand pinned in AGPRs.
__device__ inline void mfma_ag(f32x4& acc, short8 a, short8 b) {
  asm("v_mfma_f32_16x16x32_bf16 %0, %1, %2, %0"
      : "+v"(acc) : "v"(a), "a"(b));
}

// Pack Wx (k<256) and Wh (k>=256) into MFMA B-frag order.
__global__ __launch_bounds__(256) void pack_w(
    const float* __restrict__ Wf, const float* __restrict__ Wi,
    const float* __restrict__ Wg, const float* __restrict__ Wo,
    const float* __restrict__ bf_, const float* __restrict__ bi_,
    const float* __restrict__ bg_, const float* __restrict__ bo_,
    const float* __restrict__ tf_, const float* __restrict__ ti_,
    const float* __restrict__ tg_, const float* __restrict__ to_,
    bf16_t* __restrict__ Wxp, bf16_t* __restrict__ Whp,
    float* __restrict__ bias, float* __restrict__ temps)
{
  int tid = blockIdx.x * 256 + threadIdx.x;   // 65536 threads
  int half = tid >> 15;                        // 0: Wx, 1: Wh
  int idx = tid & 32767;
  int nt = idx >> 9;                           // 0..63
  int kt = (idx >> 6) & 7;
  int lane = idx & 63;
  int n = nt * 16 + (lane & 15);
  int gate = n >> 8, nrow = n & 255;
  int k = (half ? 256 : 0) + kt * 32 + (lane >> 4) * 8;
  const float* W = gate == 0 ? Wf : gate == 1 ? Wi : gate == 2 ? Wg : Wo;
  const float* src = W + (size_t)nrow * 512 + k;
  short8 d;
#pragma unroll
  for (int j = 0; j < 8; ++j) d[j] = f2bf(src[j]);
  bf16_t* dst = half ? Whp : Wxp;
  *(short8*)(dst + (size_t)idx * 8) = d;

  if (tid < 1024) {
    int g2 = tid >> 8;
    const float* bs = g2 == 0 ? bf_ : g2 == 1 ? bi_ : g2 == 2 ? bg_ : bo_;
    bias[tid] = bs[tid & 255];
  }
  if (tid < 4) {
    const float* ts = tid == 0 ? tf_ : tid == 1 ? ti_ : tid == 2 ? tg_ : to_;
    temps[tid] = ts[0];
  }
}

// theta_x GEMM: thx[trel][gg16][gate][i][lane] (uint2 = 4 bf16, C rows 0..3)
__global__ __launch_bounds__(256, 1) void gemm_thx(
    const float* __restrict__ x,        // chunk slice [CH*256, 256]
    const bf16_t* __restrict__ Wxp,
    const float* __restrict__ bias,
    bf16_t* __restrict__ thx)
{
  __shared__ bf16_t Ax[64 * 256];       // XOR-swizzled, 512 B row stride
  const int tid = threadIdx.x;
  const int wave = tid >> 6, lane = tid & 63;
  const int mb = blockIdx.x * 64;

#pragma unroll
  for (int rep = 0; rep < 16; ++rep) {
    int idx = tid + rep * 256;
    int row = idx >> 6, c4f = (idx & 63) * 4;
    float4 v = *(const float4*)(x + (size_t)(mb + row) * 256 + c4f);
    short4v d;
    d[0] = f2bf(v.x); d[1] = f2bf(v.y); d[2] = f2bf(v.z); d[3] = f2bf(v.w);
    *(short4v*)((char*)Ax + row * 512 + ((c4f * 2) ^ ((row & 7) << 4))) = d;
  }
  __syncthreads();

  short8 af[4][8];
#pragma unroll
  for (int mf = 0; mf < 4; ++mf)
#pragma unroll
    for (int kt = 0; kt < 8; ++kt) {
      int row = mf * 16 + (lane & 15);
      int kb = kt * 64 + (lane >> 4) * 16;
      af[mf][kt] = *(const short8*)((char*)Ax + row * 512 + (kb ^ ((row & 7) << 4)));
    }

  uint2* thx2 = (uint2*)thx;
#pragma unroll 1
  for (int i = 0; i < 16; ++i) {
    short8 wfr[8];
#pragma unroll
    for (int kt = 0; kt < 8; ++kt)
      wfr[kt] = *(const short8*)(Wxp + ((((size_t)(wave * 16 + i)) * 8 + kt) * 64 + lane) * 8);
    float bv = bias[wave * 256 + i * 16 + (lane & 15)];
    f32x4 ac[4];
#pragma unroll
    for (int mf = 0; mf < 4; ++mf) ac[mf] = (f32x4){0.f, 0.f, 0.f, 0.f};
#pragma unroll
    for (int kt = 0; kt < 8; ++kt)
#pragma unroll
      for (int mf = 0; mf < 4; ++mf)
        ac[mf] = __builtin_amdgcn_mfma_f32_16x16x32_bf16(af[mf][kt], wfr[kt], ac[mf], 0, 0, 0);
#pragma unroll
    for (int mf = 0; mf < 4; ++mf) {
      int mrow = mb + mf * 16;
      int trel = mrow >> 8, gg = (mrow >> 4) & 15;
      size_t di = ((((size_t)trel * 16 + gg) * 4 + wave) * 16 + i) * 64 + lane;
      uint2 pk;
      pk.x = (uint)(ushort)f2bf(ac[mf][0] + bv) |
             ((uint)(ushort)f2bf(ac[mf][1] + bv) << 16);
      pk.y = (uint)(ushort)f2bf(ac[mf][2] + bv) |
             ((uint)(ushort)f2bf(ac[mf][3] + bv) << 16);
      thx2[di] = pk;
    }
  }
}

// GEMM for one set: af rows {0,1} (rows>=2 garbage, outputs unread),
// 128 MFMA, raw theta rows (g*2+{0,1}) -> TH.
#define DO_GEMM(ASET, TX) do {                                               \
  const int arw_ = c & 1;                                                    \
  short8 af_[8];                                                             \
  _Pragma("unroll")                                                          \
  for (int kt = 0; kt < 8; ++kt)                                             \
    af_[kt] = *(const short8*)((ASET) + arw_ * 512 +                         \
                               ((kt * 64 + lg * 16) ^ (arw_ << 4)));         \
  _Pragma("unroll")                                                          \
  for (int grp = 0; grp < 4; ++grp) {                                        \
    f32x4 acc_[4];                                                           \
    _Pragma("unroll")                                                        \
    for (int qq = 0; qq < 4; ++qq) {                                         \
      uint w_ = (TX)[grp * 4 + qq];                                          \
      acc_[qq][0] = u2f(w_ << 16);                                           \
      acc_[qq][1] = u2f(w_ & 0xffff0000u);                                   \
      acc_[qq][2] = 0.f; acc_[qq][3] = 0.f;                                  \
    }                                                                        \
    _Pragma("unroll")                                                        \
    for (int qq = 0; qq < 4; ++qq)                                           \
      acc_[qq] = __builtin_amdgcn_mfma_f32_16x16x32_bf16(                    \
          af_[0], wvv[grp * 4 + qq][0], acc_[qq], 0, 0, 0);                  \
    _Pragma("unroll")                                                        \
    for (int k_ = 0; k_ < 4; ++k_)                                           \
      _Pragma("unroll")                                                      \
      for (int qq = 0; qq < 4; ++qq)                                         \
        mfma_ag(acc_[qq], af_[1 + k_], wa[grp * 4 + qq][k_]);                \
    _Pragma("unroll")                                                        \
    for (int qq = 0; qq < 4; ++qq)                                           \
      acc_[qq] = __builtin_amdgcn_mfma_f32_16x16x32_bf16(                    \
          af_[5], wvv[grp * 4 + qq][1], acc_[qq], 0, 0, 0);                  \
    _Pragma("unroll")                                                        \
    for (int k_ = 0; k_ < 2; ++k_)                                           \
      _Pragma("unroll")                                                      \
      for (int qq = 0; qq < 4; ++qq) {                                       \
        short8 bb_ = *(const short8*)(WL +                                   \
            (((g * 16 + grp * 4 + qq) * 2 + k_) * 64 + lane) * 8);           \
        acc_[qq] = __builtin_amdgcn_mfma_f32_16x16x32_bf16(                  \
            af_[6 + k_], bb_, acc_[qq], 0, 0, 0);                            \
      }                                                                      \
    if (lg == 0) {                                                           \
      _Pragma("unroll")                                                      \
      for (int qq = 0; qq < 4; ++qq) {                                       \
        TH[(g * 2 + 0) * THSTRF + (grp * 4 + qq) * 16 + c] = acc_[qq][0];    \
        TH[(g * 2 + 1) * THSTRF + (grp * 4 + qq) * 16 + c] = acc_[qq][1];    \
      }                                                                      \
    }                                                                        \
  }                                                                          \
} while (0)

// act: from pre-read va/vb (8 raw theta) -> cumprod -> activation -> ACT bf16
#define DO_ACT(VA, VB) do {                                                  \
  float vv_[8];                                                              \
  vv_[0] = __cosf((VA)[0]); vv_[1] = __cosf((VA)[1]);                        \
  vv_[2] = __cosf((VA)[2]); vv_[3] = __cosf((VA)[3]);                        \
  vv_[4] = __cosf((VB)[0]); vv_[5] = __cosf((VB)[1]);                        \
  vv_[6] = __cosf((VB)[2]); vv_[7] = __cosf((VB)[3]);                        \
  float p_ = vv_[0];                                                         \
  _Pragma("unroll")                                                          \
  for (int j = 1; j < 8; ++j) p_ *= vv_[j];                                  \
  float incl_ = p_;                                                          \
  _Pragma("unroll")                                                          \
  for (int d_ = 1; d_ < 32; d_ <<= 1) {                                      \
    float o_ = __shfl_up(incl_, d_, 32);                                     \
    if (s5 >= d_) incl_ *= o_;                                               \
  }                                                                          \
  float run_ = __shfl_up(incl_, 1, 32);                                      \
  if (s5 == 0) run_ = 1.f;                                                   \
  short8 ob_;                                                                \
  _Pragma("unroll")                                                          \
  for (int j = 0; j < 8; ++j) {                                              \
    run_ *= vv_[j];                                                          \
    float u_ = run_ * invt;                                                  \
    float a_ = isg ? fast_tanh(u_) : fast_sigmoid(u_);                       \
    ob_[j] = f2bf(a_);                                                       \
  }                                                                          \
  *(short8*)(ACT + (g * 2 + arow) * ACTSTR + s5 * 8) = ob_;                  \
} while (0)

// update one set: ACT -> c,h; write out, A, state
#define DO_UPDATE(ASET, CR, GROW0, TT, LAST) do {                            \
  const int kk_ = tid;                                                       \
  _Pragma("unroll")                                                          \
  for (int b_ = 0; b_ < 2; ++b_) {                                           \
    float fv_ = bf2fu(ACT[(0 * 2 + b_) * ACTSTR + kk_]);                     \
    float iv_ = bf2fu(ACT[(1 * 2 + b_) * ACTSTR + kk_]);                     \
    float gv_ = bf2fu(ACT[(2 * 2 + b_) * ACTSTR + kk_]);                     \
    float ov_ = bf2fu(ACT[(3 * 2 + b_) * ACTSTR + kk_]);                     \
    float cn_ = fv_ * (CR)[b_] + iv_ * gv_;                                  \
    (CR)[b_] = cn_;                                                          \
    float h_ = ov_ * fast_tanh(cn_);                                         \
    out[((size_t)(TT) * BATCH + (GROW0) + b_) * DHID + kk_] = h_;            \
    *(bf16_t*)((ASET) + b_ * 512 + ((kk_ * 2) ^ (b_ << 4))) = f2bf(h_);      \
    if ((TT) == T_STEPS - 1) {                                               \
      out[((size_t)T_STEPS * BATCH + (GROW0) + b_) * DHID + kk_] = h_;       \
      out[((size_t)T_STEPS * BATCH + BATCH + (GROW0) + b_) * DHID + kk_] = cn_; \
    }                                                                        \
    if (LAST) {                                                              \
      hG[(size_t)((GROW0) + b_) * 256 + kk_] = f2bf(h_);                     \
      cG[(size_t)((GROW0) + b_) * 256 + kk_] = cn_;                          \
    }                                                                        \
  }                                                                          \
} while (0)

// Recurrent kernel: 64 WGs x 256 thr (4 waves, 1/SIMD). Wave = gate.
// Two phase-shifted 2-row recurrences per WG (ILP across MFMA/VALU pipes).
__global__ __launch_bounds__(NTHREADS, 1) void qlstm_rec(
    const bf16_t* __restrict__ thx,
    const bf16_t* __restrict__ Whp,
    const float* __restrict__ temps,
    bf16_t* __restrict__ hG, float* __restrict__ cG,
    float* __restrict__ out,
    int t0, int nsteps)
{
  extern __shared__ char smem[];
  bf16_t* WL = (bf16_t*)(smem + OFF_WL);
  char*   AP = smem + OFF_AP;
  char*   AQ = smem + OFF_AQ;
  float*  TH = (float*)(smem + OFF_TH);
  ushort* ACT = (ushort*)(smem + OFF_ACT);

  const int tid = threadIdx.x;
  const int g = tid >> 6, lane = tid & 63;
  const int lg = lane >> 4, c = lane & 15;
  const int arow = lane >> 5, s5 = lane & 31;     // act mapping
  const int gg4 = blockIdx.x;
  const int gg16 = gg4 >> 2, q = gg4 & 3;
  const int rowP = gg16 * 16 + q * 4;             // global row of P[0]
  const int rowQ = rowP + 2;

  // ---- Wh residency: kt1-4 AGPR, kt0/5 VGPR, kt6/7 LDS ----
  short8 wa[16][4];
#pragma unroll
  for (int i = 0; i < 16; ++i)
#pragma unroll
    for (int k = 0; k < 4; ++k)
      wa[i][k] = *(const short8*)(Whp + ((((size_t)(g * 16 + i)) * 8 + (k + 1)) * 64 + lane) * 8);
  short8 wvv[16][2];
#pragma unroll
  for (int i = 0; i < 16; ++i) {
    wvv[i][0] = *(const short8*)(Whp + ((((size_t)(g * 16 + i)) * 8 + 0) * 64 + lane) * 8);
    wvv[i][1] = *(const short8*)(Whp + ((((size_t)(g * 16 + i)) * 8 + 5) * 64 + lane) * 8);
  }
#pragma unroll
  for (int i = 0; i < 16; ++i)
#pragma unroll
    for (int k = 0; k < 2; ++k)
      *(short8*)(WL + (((g * 16 + i) * 2 + k) * 64 + lane) * 8) =
          *(const short8*)(Whp + ((((size_t)(g * 16 + i)) * 8 + (6 + k)) * 64 + lane) * 8);

  const float invt = frcp(temps[g]);
  const bool isg = (g == 2);

  // ---- init A (h) both sets, C regs ----
  {
    int set = tid >> 7, b = (tid >> 6) & 1, k0 = (tid & 63) * 4;
    int grow = (set ? rowQ : rowP) + b;
    uint2 hv = make_uint2(0u, 0u);
    if (t0 != 0) hv = *(const uint2*)(hG + (size_t)grow * 256 + k0);
    char* As = set ? AQ : AP;
    *(uint2*)(As + b * 512 + ((k0 * 2) ^ (b << 4))) = hv;
  }
  float cP[2] = {0.f, 0.f}, cQ[2] = {0.f, 0.f};
  if (t0 != 0) {
    cP[0] = cG[(size_t)(rowP + 0) * 256 + tid];
    cP[1] = cG[(size_t)(rowP + 1) * 256 + tid];
    cQ[0] = cG[(size_t)(rowQ + 0) * 256 + tid];
    cQ[1] = cG[(size_t)(rowQ + 1) * 256 + tid];
  }

  // ---- tx: per-set 16x u32 (rows 0,1 in .x, rows 2,3 in .y) ----
  const uint* thw = (const uint*)thx;
  const size_t txstep = (size_t)16 * 4 * 1024 * 2;   // uints per t
  const size_t txbase = (((size_t)gg16 * 4 + g) * 1024 + q * 16 + c) * 2;
  uint txP[16], txQ[16];
#pragma unroll
  for (int i = 0; i < 16; ++i) {
    txP[i] = thw[txbase + i * 128 + 0];
    txQ[i] = thw[txbase + i * 128 + 1];
  }
  __syncthreads();

  // ---- prologue: GEMM_Q(0) -> TH ----
  DO_GEMM(AQ, txQ);

#pragma unroll 1
  for (int i = 0; i < nsteps; ++i) {
    const int t = t0 + i;
    const int ip1 = (i + 1 < nsteps) ? i + 1 : i;
    const bool last = (i == nsteps - 1);

    // ---- ph1: read Q raw, fence; GEMM_P(i) || act_Q(i); prefetch txQ(i+1)
    {
      const float* rq = TH + (g * 2 + arow) * THSTRF + s5 * 8;
      f32x4 va = *(const f32x4*)rq;
      f32x4 vb = *(const f32x4*)(rq + 4);
      asm volatile("s_waitcnt lgkmcnt(0)" ::: "memory");
      __builtin_amdgcn_sched_barrier(0);
#pragma unroll
      for (int j = 0; j < 16; ++j)
        txQ[j] = thw[(size_t)ip1 * txstep + txbase + j * 128 + 1];
      DO_GEMM(AP, txP);
      DO_ACT(va, vb);
    }
    __syncthreads();   // B1: ACT_Q ready

    DO_UPDATE(AQ, cQ, rowQ, t, last);
    __syncthreads();   // B2: A_Q(t+1) ready, ACT free

    // ---- ph3: read P raw, fence; GEMM_Q(i+1) || act_P(i); prefetch txP(i+1)
    {
      const float* rq = TH + (g * 2 + arow) * THSTRF + s5 * 8;
      f32x4 va = *(const f32x4*)rq;
      f32x4 vb = *(const f32x4*)(rq + 4);
      asm volatile("s_waitcnt lgkmcnt(0)" ::: "memory");
      __builtin_amdgcn_sched_barrier(0);
#pragma unroll
      for (int j = 0; j < 16; ++j)
        txP[j] = thw[(size_t)ip1 * txstep + txbase + j * 128 + 0];
      DO_GEMM(AQ, txQ);
      DO_ACT(va, vb);
    }
    __syncthreads();   // B3: ACT_P ready

    DO_UPDATE(AP, cP, rowP, t, last);
    __syncthreads();   // B4: A_P(t+1) ready, ACT free
  }
}

extern "C" void kernel_launch(void* const* d_in, const int* in_sizes, int n_in,
                              void* d_out, int out_size, void* d_ws, size_t ws_size,
                              hipStream_t stream) {
  (void)in_sizes; (void)n_in; (void)out_size;
  const float* x   = (const float*)d_in[0];
  const float* Wf  = (const float*)d_in[1];
  const float* bf_ = (const float*)d_in[2];
  const float* tf_ = (const float*)d_in[3];
  const float* Wi  = (const float*)d_in[4];
  const float* bi_ = (const float*)d_in[5];
  const float* ti_ = (const float*)d_in[6];
  const float* Wg  = (const float*)d_in[7];
  const float* bg_ = (const float*)d_in[8];
  const float* tg_ = (const float*)d_in[9];
  const float* Wo  = (const float*)d_in[10];
  const float* bo_ = (const float*)d_in[11];
  const float* to_ = (const float*)d_in[12];

  char* ws = (char*)d_ws;
  bf16_t* Whp   = (bf16_t*)(ws + WS_WHP);
  bf16_t* Wxp   = (bf16_t*)(ws + WS_WXP);
  float*  bias  = (float*)(ws + WS_BIAS);
  float*  temps = (float*)(ws + WS_TMP);
  bf16_t* hG    = (bf16_t*)(ws + WS_HG);
  float*  cG    = (float*)(ws + WS_CG);
  bf16_t* thx   = (bf16_t*)(ws + WS_THX);

  size_t avail = ws_size > (size_t)(2u << 20) ? ws_size - (size_t)(2u << 20) : 0;
  int CH = 4;
  const int cands[6] = {128, 64, 32, 16, 8, 4};
  for (int ci = 0; ci < 6; ++ci)
    if ((size_t)cands[ci] * 512 * 1024 <= avail) { CH = cands[ci]; break; }

  hipLaunchKernelGGL(pack_w, dim3(256), dim3(256), 0, stream,
                     Wf, Wi, Wg, Wo, bf_, bi_, bg_, bo_, tf_, ti_, tg_, to_,
                     Wxp, Whp, bias, temps);

  (void)hipFuncSetAttribute((const void*)qlstm_rec,
                            hipFuncAttributeMaxDynamicSharedMemorySize,
                            LDS_REC);

  for (int c0 = 0; c0 < T_STEPS; c0 += CH) {
    hipLaunchKernelGGL(gemm_thx, dim3(CH * 4), dim3(256), 0, stream,
                       x + (size_t)c0 * BATCH * DIN, Wxp, bias, thx);
    hipLaunchKernelGGL(qlstm_rec, dim3(NWG), dim3(256), LDS_REC, stream,
                       thx, Whp, temps, hG, cG, (float*)d_out, c0, CH);
  }
}

// Round 7
// 2833.847 us; speedup vs baseline: 1.4918x; 1.4918x over previous
//
#include <hip/hip_runtime.h>

#define T_STEPS 512
#define BATCH   256
#define DIN     256
#define DHID    256
#define BBLK    2        // batch rows per WG
#define NWG     128      // BATCH / BBLK
#define NTHREADS 512     // 8 waves: wave = (gate, n-half)

typedef short bf16_t;
typedef __attribute__((ext_vector_type(4))) short short4v;
typedef __attribute__((ext_vector_type(8))) short short8;
typedef __attribute__((ext_vector_type(4))) float f32x4;
typedef unsigned int uint;
typedef unsigned short ushort;

// ---- REC LDS layout (bytes) ----
#define OFF_WL  0
#define SZ_WL   (4 * 16 * 2 * 64 * 16)      // 131072: kt6,7 frags all gates
#define OFF_A   (OFF_WL + SZ_WL)            // A: 2 rows x 512 B (XOR swizzled)
#define SZ_A    1024
#define OFF_TH  (OFF_A + SZ_A)              // raw theta f32 [8 rows][320]
#define THSTR   320                         // 256 + 4 pad per 16 block
#define SZ_TH   (8 * THSTR * 4)             // 10240
#define OFF_ACT (OFF_TH + SZ_TH)            // act bf16 [8 rows][256]
#define SZ_ACT  (8 * 256 * 2)               // 4096
#define LDS_REC (OFF_ACT + SZ_ACT)          // 146432

#define TXSTEP  131072                      // uints per t in thx

// ---- workspace layout (bytes) ----
#define WS_WHP   0u                        // 512 KB Wh packed (B-frag order)
#define WS_WXP   (512u << 10)              // 512 KB Wx packed
#define WS_BIAS  (1u << 20)                // 4 KB
#define WS_TMP   ((1u << 20) + 4096u)      // 16 B
#define WS_HG    ((1u << 20) + 8192u)      // 128 KB h state bf16 [256][256]
#define WS_CG    ((1u << 20) + 8192u + 131072u)  // 256 KB c state f32
#define WS_THX   (2u << 20)                // CH*512 KB theta_x chunk

__device__ inline short f2bf(float f) {
  union { float f; uint u; } v; v.f = f;
  uint r = (v.u + 0x7FFFu + ((v.u >> 16) & 1u)) >> 16;
  return (short)r;
}
__device__ inline float bf2fu(ushort s) {
  union { float f; uint u; } v; v.u = ((uint)s) << 16;
  return v.f;
}
__device__ inline float u2f(uint u) {
  union { float f; uint u; } v; v.u = u; return v.f;
}
__device__ inline float frcp(float x) { return __builtin_amdgcn_rcpf(x); }
__device__ inline float fast_sigmoid(float x) { return frcp(1.f + __expf(-x)); }
__device__ inline float fast_tanh(float x) {
  float ax = fabsf(x);
  float e = __expf(2.f * ax);              // inf-safe
  float r = 1.f - 2.f * frcp(e + 1.f);
  return copysignf(r, x);
}

// asm MFMA with B operand pinned in AGPRs (round-5 proven).
__device__ inline void mfma_ag(f32x4& acc, short8 a, short8 b) {
  asm("v_mfma_f32_16x16x32_bf16 %0, %1, %2, %0"
      : "+v"(acc) : "v"(a), "a"(b));
}

// Pack Wx (k<256) and Wh (k>=256) into MFMA B-frag order.
// frag(nt, kt): elem[((nt*8+kt)*64+lane)*8 + j] = W[n][k],
//   n = nt*16 + (lane&15), k = kbase + kt*32 + (lane>>4)*8 + j.
__global__ __launch_bounds__(256) void pack_w(
    const float* __restrict__ Wf, const float* __restrict__ Wi,
    const float* __restrict__ Wg, const float* __restrict__ Wo,
    const float* __restrict__ bf_, const float* __restrict__ bi_,
    const float* __restrict__ bg_, const float* __restrict__ bo_,
    const float* __restrict__ tf_, const float* __restrict__ ti_,
    const float* __restrict__ tg_, const float* __restrict__ to_,
    bf16_t* __restrict__ Wxp, bf16_t* __restrict__ Whp,
    float* __restrict__ bias, float* __restrict__ temps)
{
  int tid = blockIdx.x * 256 + threadIdx.x;   // 65536 threads
  int half = tid >> 15;                        // 0: Wx, 1: Wh
  int idx = tid & 32767;
  int nt = idx >> 9;                           // 0..63
  int kt = (idx >> 6) & 7;
  int lane = idx & 63;
  int n = nt * 16 + (lane & 15);
  int gate = n >> 8, nrow = n & 255;
  int k = (half ? 256 : 0) + kt * 32 + (lane >> 4) * 8;
  const float* W = gate == 0 ? Wf : gate == 1 ? Wi : gate == 2 ? Wg : Wo;
  const float* src = W + (size_t)nrow * 512 + k;
  short8 d;
#pragma unroll
  for (int j = 0; j < 8; ++j) d[j] = f2bf(src[j]);
  bf16_t* dst = half ? Whp : Wxp;
  *(short8*)(dst + (size_t)idx * 8) = d;

  if (tid < 1024) {
    int g2 = tid >> 8;
    const float* bs = g2 == 0 ? bf_ : g2 == 1 ? bi_ : g2 == 2 ? bg_ : bo_;
    bias[tid] = bs[tid & 255];
  }
  if (tid < 4) {
    const float* ts = tid == 0 ? tf_ : tid == 1 ? ti_ : tid == 2 ? tg_ : to_;
    temps[tid] = ts[0];
  }
}

// theta_x GEMM. Output layout: thx[trel][gg16][q8][g][i][c] (uint = 2 rows
// bf16-packed, rows (2*q8, 2*q8+1) of batch-group gg16).
__global__ __launch_bounds__(256, 1) void gemm_thx(
    const float* __restrict__ x,        // chunk slice [CH*256, 256]
    const bf16_t* __restrict__ Wxp,
    const float* __restrict__ bias,
    uint* __restrict__ thxU)
{
  __shared__ bf16_t Ax[64 * 256];       // XOR-swizzled, 512 B row stride
  const int tid = threadIdx.x;
  const int wave = tid >> 6, lane = tid & 63;
  const int lg = lane >> 4, c = lane & 15;
  const int mb = blockIdx.x * 64;

#pragma unroll
  for (int rep = 0; rep < 16; ++rep) {
    int idx = tid + rep * 256;
    int row = idx >> 6, c4f = (idx & 63) * 4;
    float4 v = *(const float4*)(x + (size_t)(mb + row) * 256 + c4f);
    short4v d;
    d[0] = f2bf(v.x); d[1] = f2bf(v.y); d[2] = f2bf(v.z); d[3] = f2bf(v.w);
    *(short4v*)((char*)Ax + row * 512 + ((c4f * 2) ^ ((row & 7) << 4))) = d;
  }
  __syncthreads();

  short8 af[4][8];
#pragma unroll
  for (int mf = 0; mf < 4; ++mf)
#pragma unroll
    for (int kt = 0; kt < 8; ++kt) {
      int row = mf * 16 + (lane & 15);
      int kb = kt * 64 + (lane >> 4) * 16;
      af[mf][kt] = *(const short8*)((char*)Ax + row * 512 + (kb ^ ((row & 7) << 4)));
    }

#pragma unroll 1
  for (int i = 0; i < 16; ++i) {
    short8 wfr[8];
#pragma unroll
    for (int kt = 0; kt < 8; ++kt)
      wfr[kt] = *(const short8*)(Wxp + ((((size_t)(wave * 16 + i)) * 8 + kt) * 64 + lane) * 8);
    float bv = bias[wave * 256 + i * 16 + c];
    f32x4 ac[4];
#pragma unroll
    for (int mf = 0; mf < 4; ++mf) ac[mf] = (f32x4){0.f, 0.f, 0.f, 0.f};
#pragma unroll
    for (int kt = 0; kt < 8; ++kt)
#pragma unroll
      for (int mf = 0; mf < 4; ++mf)
        ac[mf] = __builtin_amdgcn_mfma_f32_16x16x32_bf16(af[mf][kt], wfr[kt], ac[mf], 0, 0, 0);
#pragma unroll
    for (int mf = 0; mf < 4; ++mf) {
      int mrow = mb + mf * 16;
      int trel = mrow >> 8, gg = (mrow >> 4) & 15;
      uint pk0 = (uint)(ushort)f2bf(ac[mf][0] + bv) |
                 ((uint)(ushort)f2bf(ac[mf][1] + bv) << 16);
      uint pk1 = (uint)(ushort)f2bf(ac[mf][2] + bv) |
                 ((uint)(ushort)f2bf(ac[mf][3] + bv) << 16);
      size_t ibase = ((size_t)trel * 16 + gg) * 8;
      thxU[((ibase + lg * 2 + 0) * 4 + wave) * 256 + i * 16 + c] = pk0;
      thxU[((ibase + lg * 2 + 1) * 4 + wave) * 256 + i * 16 + c] = pk1;
    }
  }
}

// Recurrent kernel: 128 WGs x 512 thr (8 waves, 2/SIMD). Wave = (gate, n-half).
// Wh per wave: 8 ntiles x {kt0-5 AGPR (192), kt6-7 LDS}.
__global__ __launch_bounds__(NTHREADS, 2) void qlstm_rec(
    const uint* __restrict__ thxU,
    const bf16_t* __restrict__ Whp,
    const float* __restrict__ temps,
    bf16_t* __restrict__ hG, float* __restrict__ cG,
    float* __restrict__ out,
    int t0, int nsteps)
{
  extern __shared__ char smem[];
  bf16_t* WL = (bf16_t*)(smem + OFF_WL);
  char*   Ab = smem + OFF_A;
  float*  TH = (float*)(smem + OFF_TH);
  ushort* ACT = (ushort*)(smem + OFF_ACT);

  const int tid = threadIdx.x;
  const int wv = tid >> 6, lane = tid & 63;
  const int g = wv >> 1, hh = wv & 1;
  const int lg = lane >> 4, c = lane & 15;
  const int bid = blockIdx.x;
  const int gg16 = bid >> 3, q8 = bid & 7;
  const int b0 = bid * BBLK;

  // ---- Wh residency: kt0..5 -> AGPR (asm-pinned), kt6,7 -> LDS ----
  short8 wa[8][6];
#pragma unroll
  for (int j = 0; j < 8; ++j)
#pragma unroll
    for (int kt = 0; kt < 6; ++kt)
      wa[j][kt] = *(const short8*)(Whp +
          ((((size_t)(g * 16 + hh * 8 + j)) * 8 + kt) * 64 + lane) * 8);
#pragma unroll
  for (int j = 0; j < 8; ++j)
#pragma unroll
    for (int k = 0; k < 2; ++k)
      *(short8*)(WL + (((g * 16 + hh * 8 + j) * 2 + k) * 64 + lane) * 8) =
          *(const short8*)(Whp +
              ((((size_t)(g * 16 + hh * 8 + j)) * 8 + (6 + k)) * 64 + lane) * 8);

  const float invt = frcp(temps[g]);
  const bool isg = (g == 2);

  // ---- init A (h) and c ----
  const int ub = tid >> 8, ukk = tid & 255;   // update/init mapping
  float creg;
  {
    short hv = 0; float cv = 0.f;
    if (t0 != 0) {
      hv = hG[(size_t)(b0 + ub) * 256 + ukk];
      cv = cG[(size_t)(b0 + ub) * 256 + ukk];
    }
    *(bf16_t*)(Ab + ub * 512 + ((ukk * 2) ^ (ub << 4))) = hv;
    creg = cv;
  }

  // ---- theta_x: 8 uints per lane per step ----
  const size_t txbase = ((((size_t)gg16) * 8 + q8) * 4 + g) * 256;
  uint tx[8], txn[8];
#pragma unroll
  for (int j = 0; j < 8; ++j)
    tx[j] = thxU[(size_t)t0 * 0 + txbase + (hh * 8 + j) * 16 + c];
  __syncthreads();

#pragma unroll 1
  for (int ts = 0; ts < nsteps; ++ts) {
    const int t = t0 + ts;
    const bool last = (ts == nsteps - 1);

    // ---- GEMM: theta = theta_x + h @ Wh^T (this wave's 8 ntiles) ----
#pragma unroll
    for (int ntg = 0; ntg < 2; ++ntg) {
      f32x4 acc[4];
#pragma unroll
      for (int q = 0; q < 4; ++q) {
        uint w = tx[ntg * 4 + q];
        acc[q][0] = u2f(w << 16);
        acc[q][1] = u2f(w & 0xffff0000u);
        acc[q][2] = 0.f; acc[q][3] = 0.f;
      }
      // kt6 (builtin, LDS B) — compiler guards VALU->MFMA SrcC hazard
      {
        short8 af6 = *(const short8*)(Ab + (c & 1) * 512 +
                                      ((6 * 64 + lg * 16) ^ ((c & 1) << 4)));
#pragma unroll
        for (int q = 0; q < 4; ++q) {
          short8 b = *(const short8*)(WL +
              (((g * 16 + hh * 8 + ntg * 4 + q) * 2 + 0) * 64 + lane) * 8);
          acc[q] = __builtin_amdgcn_mfma_f32_16x16x32_bf16(af6, b, acc[q], 0, 0, 0);
        }
      }
      // kt0..5 (asm, AGPR B) — MAI->MAI chains need no waits
#pragma unroll
      for (int kt = 0; kt < 6; ++kt) {
        short8 af = *(const short8*)(Ab + (c & 1) * 512 +
                                     ((kt * 64 + lg * 16) ^ ((c & 1) << 4)));
#pragma unroll
        for (int q = 0; q < 4; ++q)
          mfma_ag(acc[q], af, wa[ntg * 4 + q][kt]);
      }
      // kt7 (builtin, LDS B) — compiler guards trailing MFMA->VALU hazard
      {
        short8 af7 = *(const short8*)(Ab + (c & 1) * 512 +
                                      ((7 * 64 + lg * 16) ^ ((c & 1) << 4)));
#pragma unroll
        for (int q = 0; q < 4; ++q) {
          short8 b = *(const short8*)(WL +
              (((g * 16 + hh * 8 + ntg * 4 + q) * 2 + 1) * 64 + lane) * 8);
          acc[q] = __builtin_amdgcn_mfma_f32_16x16x32_bf16(af7, b, acc[q], 0, 0, 0);
        }
      }
      // store raw theta rows 0,1 (valid in lg==0 lanes)
      if (lg == 0) {
#pragma unroll
        for (int q = 0; q < 4; ++q) {
          int n = hh * 128 + (ntg * 4 + q) * 16 + c;
          int p = n + ((n >> 4) << 2);
          TH[(g * 2 + 0) * THSTR + p] = acc[q][0];
          TH[(g * 2 + 1) * THSTR + p] = acc[q][1];
        }
      }
    }

    // ---- prefetch next step's theta_x ----
    {
      int tsn = (ts + 1 < nsteps) ? ts + 1 : ts;
#pragma unroll
      for (int j = 0; j < 8; ++j)
        txn[j] = thxU[(size_t)tsn * TXSTEP + txbase + (hh * 8 + j) * 16 + c];
    }
    __syncthreads();   // B0: TH complete (both n-halves)

    // ---- act: wave handles chain (g, row=hh); lane: n in [4l, 4l+4) ----
    {
      const int n0 = lane * 4;
      const int p = n0 + ((n0 >> 4) << 2);
      f32x4 v = *(const f32x4*)(TH + (g * 2 + hh) * THSTR + p);
      float vv0 = __cosf(v[0]), vv1 = __cosf(v[1]);
      float vv2 = __cosf(v[2]), vv3 = __cosf(v[3]);
      float sp = vv0 * vv1 * vv2 * vv3;
      float incl = sp;
#pragma unroll
      for (int d = 1; d < 64; d <<= 1) {
        float o = __shfl_up(incl, d);
        if (lane >= d) incl *= o;
      }
      float run = __shfl_up(incl, 1);
      if (lane == 0) run = 1.f;
      short4v ob;
      run *= vv0; ob[0] = f2bf(isg ? fast_tanh(run * invt) : fast_sigmoid(run * invt));
      run *= vv1; ob[1] = f2bf(isg ? fast_tanh(run * invt) : fast_sigmoid(run * invt));
      run *= vv2; ob[2] = f2bf(isg ? fast_tanh(run * invt) : fast_sigmoid(run * invt));
      run *= vv3; ob[3] = f2bf(isg ? fast_tanh(run * invt) : fast_sigmoid(run * invt));
      *(short4v*)(ACT + (g * 2 + hh) * 256 + n0) = ob;
    }
    __syncthreads();   // B1: ACT ready

    // ---- update: thread (ub, ukk) ----
    {
      float fv = bf2fu(ACT[(0 * 2 + ub) * 256 + ukk]);
      float iv = bf2fu(ACT[(1 * 2 + ub) * 256 + ukk]);
      float gv = bf2fu(ACT[(2 * 2 + ub) * 256 + ukk]);
      float ov = bf2fu(ACT[(3 * 2 + ub) * 256 + ukk]);
      float cn = fv * creg + iv * gv;
      creg = cn;
      float h = ov * fast_tanh(cn);
      out[((size_t)t * BATCH + b0 + ub) * DHID + ukk] = h;
      *(bf16_t*)(Ab + ub * 512 + ((ukk * 2) ^ (ub << 4))) = f2bf(h);
      if (t == T_STEPS - 1) {
        out[((size_t)T_STEPS * BATCH + b0 + ub) * DHID + ukk] = h;
        out[((size_t)T_STEPS * BATCH + BATCH + b0 + ub) * DHID + ukk] = cn;
      }
      if (last) {
        hG[(size_t)(b0 + ub) * 256 + ukk] = f2bf(h);
        cG[(size_t)(b0 + ub) * 256 + ukk] = cn;
      }
    }
    __syncthreads();   // B2: A(t+1) complete

#pragma unroll
    for (int j = 0; j < 8; ++j) tx[j] = txn[j];
  }
}

extern "C" void kernel_launch(void* const* d_in, const int* in_sizes, int n_in,
                              void* d_out, int out_size, void* d_ws, size_t ws_size,
                              hipStream_t stream) {
  (void)in_sizes; (void)n_in; (void)out_size;
  const float* x   = (const float*)d_in[0];
  const float* Wf  = (const float*)d_in[1];
  const float* bf_ = (const float*)d_in[2];
  const float* tf_ = (const float*)d_in[3];
  const float* Wi  = (const float*)d_in[4];
  const float* bi_ = (const float*)d_in[5];
  const float* ti_ = (const float*)d_in[6];
  const float* Wg  = (const float*)d_in[7];
  const float* bg_ = (const float*)d_in[8];
  const float* tg_ = (const float*)d_in[9];
  const float* Wo  = (const float*)d_in[10];
  const float* bo_ = (const float*)d_in[11];
  const float* to_ = (const float*)d_in[12];

  char* ws = (char*)d_ws;
  bf16_t* Whp   = (bf16_t*)(ws + WS_WHP);
  bf16_t* Wxp   = (bf16_t*)(ws + WS_WXP);
  float*  bias  = (float*)(ws + WS_BIAS);
  float*  temps = (float*)(ws + WS_TMP);
  bf16_t* hG    = (bf16_t*)(ws + WS_HG);
  float*  cG    = (float*)(ws + WS_CG);
  uint*   thxU  = (uint*)(ws + WS_THX);

  size_t avail = ws_size > (size_t)(2u << 20) ? ws_size - (size_t)(2u << 20) : 0;
  int CH = 4;
  const int cands[6] = {128, 64, 32, 16, 8, 4};
  for (int ci = 0; ci < 6; ++ci)
    if ((size_t)cands[ci] * 512 * 1024 <= avail) { CH = cands[ci]; break; }

  hipLaunchKernelGGL(pack_w, dim3(256), dim3(256), 0, stream,
                     Wf, Wi, Wg, Wo, bf_, bi_, bg_, bo_, tf_, ti_, tg_, to_,
                     Wxp, Whp, bias, temps);

  (void)hipFuncSetAttribute((const void*)qlstm_rec,
                            hipFuncAttributeMaxDynamicSharedMemorySize,
                            LDS_REC);

  for (int c0 = 0; c0 < T_STEPS; c0 += CH) {
    hipLaunchKernelGGL(gemm_thx, dim3(CH * 4), dim3(256), 0, stream,
                       x + (size_t)c0 * BATCH * DIN, Wxp, bias, thxU);
    hipLaunchKernelGGL(qlstm_rec, dim3(NWG), dim3(NTHREADS), LDS_REC, stream,
                       thxU, Whp, temps, hG, cG, (float*)d_out, c0, CH);
  }
}

// Round 9
// 1480.883 us; speedup vs baseline: 2.8548x; 1.9136x over previous
//
#include <hip/hip_runtime.h>

#define T_STEPS 512
#define BATCH   256
#define DIN     256
#define DHID    256
#define BBLK    4        // batch rows per WG
#define NWG     64       // BATCH / BBLK
#define NTHREADS 512     // 8 waves: wave = (gate, n-half), 2 waves/SIMD

typedef short bf16_t;
typedef __attribute__((ext_vector_type(4))) short short4v;
typedef __attribute__((ext_vector_type(8))) short short8;
typedef __attribute__((ext_vector_type(4))) float f32x4;
typedef __attribute__((ext_vector_type(4))) int int32x4;
typedef unsigned int uint;
typedef unsigned short ushort;

// ---- workspace layout (bytes) ----
#define WS_WXP  0u                   // 512 KB bf16 Wx frags
#define WS_WHQ  (512u << 10)         // 256 KB i8 Wh frags
#define WS_SW   (768u << 10)         // 4 KB f32 sW[1024] (amax/127^2: W AND h dequant)
#define WS_RQ   (772u << 10)         // 4 KB f32 rq[1024] (127/amax)
#define WS_BIAS (776u << 10)         // 4 KB
#define WS_TMP  (780u << 10)         // 16 B
#define WS_HGQ  (784u << 10)         // 64 KB i8 h state [256][256]
#define WS_CG   (848u << 10)         // 256 KB f32 c state
#define WS_THX  (2u << 20)           // CH*512KB theta_x chunk

#define TXSTEP  65536                // uint2 per t in thx

__device__ inline short f2bf(float f) {
  union { float f; uint u; } v; v.f = f;
  uint r = (v.u + 0x7FFFu + ((v.u >> 16) & 1u)) >> 16;
  return (short)r;
}
__device__ inline float bf2fu(ushort s) {
  union { float f; uint u; } v; v.u = ((uint)s) << 16;
  return v.f;
}
__device__ inline float u2f(uint u) {
  union { float f; uint u; } v; v.u = u; return v.f;
}
__device__ inline float frcp(float x) { return __builtin_amdgcn_rcpf(x); }
__device__ inline float fast_sigmoid(float x) { return frcp(1.f + __expf(-x)); }
__device__ inline float fast_tanh(float x) {
  float ax = fabsf(x);
  float e = __expf(2.f * ax);              // inf-safe
  float r = 1.f - 2.f * frcp(e + 1.f);
  return copysignf(r, x);
}

// asm i8 MFMA with B operand pinned in AGPRs (round-5/7-proven pattern:
// chains bookended by builtins so the compiler guards VALU<->MFMA hazards).
__device__ inline void mfma_i8_a(int32x4& acc, int32x4 a, int32x4 b) {
  asm("v_mfma_i32_16x16x64_i8 %0, %1, %2, %0"
      : "+v"(acc) : "v"(a), "a"(b));
}

// ---- per-row amax scales for Wh (k in [256,512)) ----
// sw = amax / 127^2: dequant for BOTH W (x127/amax) and h (x127) quant steps.
__global__ __launch_bounds__(256) void k_scales(
    const float* __restrict__ Wf, const float* __restrict__ Wi,
    const float* __restrict__ Wg, const float* __restrict__ Wo,
    float* __restrict__ sw, float* __restrict__ rq)
{
  int n = blockIdx.x * 256 + threadIdx.x;       // 0..1023
  int gate = n >> 8, nrow = n & 255;
  const float* W = gate == 0 ? Wf : gate == 1 ? Wi : gate == 2 ? Wg : Wo;
  const float4* row = (const float4*)(W + (size_t)nrow * 512 + 256);
  float amax = 0.f;
#pragma unroll 4
  for (int k = 0; k < 64; ++k) {
    float4 v = row[k];
    amax = fmaxf(amax, fmaxf(fmaxf(fabsf(v.x), fabsf(v.y)),
                             fmaxf(fabsf(v.z), fabsf(v.w))));
  }
  sw[n] = amax / (127.f * 127.f);
  rq[n] = amax > 0.f ? 127.f / amax : 0.f;
}

// ---- pack Wx (k<256) into bf16 MFMA B-frag order + bias + temps ----
// frag(nt, kt): elem[((nt*8+kt)*64+lane)*8 + j] = W[n][k],
//   n = nt*16+(lane&15), k = kt*32 + (lane>>4)*8 + j.
__global__ __launch_bounds__(256) void k_packx(
    const float* __restrict__ Wf, const float* __restrict__ Wi,
    const float* __restrict__ Wg, const float* __restrict__ Wo,
    const float* __restrict__ bf_, const float* __restrict__ bi_,
    const float* __restrict__ bg_, const float* __restrict__ bo_,
    const float* __restrict__ tf_, const float* __restrict__ ti_,
    const float* __restrict__ tg_, const float* __restrict__ to_,
    bf16_t* __restrict__ Wxp, float* __restrict__ bias,
    float* __restrict__ temps)
{
  int tid = blockIdx.x * 256 + threadIdx.x;     // 0..32767
  int nt = tid >> 9;
  int kt = (tid >> 6) & 7;
  int lane = tid & 63;
  int n = nt * 16 + (lane & 15);
  int gate = n >> 8, nrow = n & 255;
  int k = kt * 32 + (lane >> 4) * 8;
  const float* W = gate == 0 ? Wf : gate == 1 ? Wi : gate == 2 ? Wg : Wo;
  const float* src = W + (size_t)nrow * 512 + k;
  short8 d;
#pragma unroll
  for (int j = 0; j < 8; ++j) d[j] = f2bf(src[j]);
  *(short8*)(Wxp + (size_t)tid * 8) = d;

  if (tid < 1024) {
    int g2 = tid >> 8;
    const float* bs = g2 == 0 ? bf_ : g2 == 1 ? bi_ : g2 == 2 ? bg_ : bo_;
    bias[tid] = bs[tid & 255];
  }
  if (tid < 4) {
    const float* ts = tid == 0 ? tf_ : tid == 1 ? ti_ : tid == 2 ? tg_ : to_;
    temps[tid] = ts[0];
  }
}

// ---- pack Wh (k in [256,512)) into i8 16x16x64 B-frag order ----
// frag(nt, kt): 16B elem[(nt*4+kt)*64+lane] = Wq[n][k0..k0+15],
//   n = nt*16+(lane&15), k0 = 256 + kt*64 + (lane>>4)*16.
__global__ __launch_bounds__(256) void k_packh(
    const float* __restrict__ Wf, const float* __restrict__ Wi,
    const float* __restrict__ Wg, const float* __restrict__ Wo,
    const float* __restrict__ rq, signed char* __restrict__ Whq)
{
  int tid = blockIdx.x * 256 + threadIdx.x;     // 0..16383
  int nt = tid >> 8;
  int kt = (tid >> 6) & 3;
  int lane = tid & 63;
  int n = nt * 16 + (lane & 15);
  int gate = n >> 8, nrow = n & 255;
  int k0 = 256 + kt * 64 + (lane >> 4) * 16;
  const float* W = gate == 0 ? Wf : gate == 1 ? Wi : gate == 2 ? Wg : Wo;
  const float* src = W + (size_t)nrow * 512 + k0;
  float r = rq[n];
  union { signed char b[16]; int32x4 v; } pk;
#pragma unroll
  for (int j = 0; j < 16; ++j) {
    int qi = __float2int_rn(src[j] * r);
    qi = qi > 127 ? 127 : (qi < -127 ? -127 : qi);
    pk.b[j] = (signed char)qi;
  }
  *(int32x4*)(Whq + (size_t)tid * 16) = pk.v;
}

// ---- theta_x GEMM; store layout: uint2[trel][gg64][g4][hh2][j8][c16]
//      = 4 batch rows (bf16 pairs) of column n=(g*16+hh*8+j)*16+c.
__global__ __launch_bounds__(256, 1) void gemm_thx(
    const float* __restrict__ x,        // chunk slice [CH*256, 256]
    const bf16_t* __restrict__ Wxp,
    const float* __restrict__ bias,
    uint2* __restrict__ thx2)
{
  __shared__ bf16_t Ax[64 * 256];       // XOR-swizzled, 512 B row stride
  const int tid = threadIdx.x;
  const int wave = tid >> 6, lane = tid & 63;
  const int lg = lane >> 4, c = lane & 15;
  const int mb = blockIdx.x * 64;

#pragma unroll
  for (int rep = 0; rep < 16; ++rep) {
    int idx = tid + rep * 256;
    int row = idx >> 6, c4f = (idx & 63) * 4;
    float4 v = *(const float4*)(x + (size_t)(mb + row) * 256 + c4f);
    short4v d;
    d[0] = f2bf(v.x); d[1] = f2bf(v.y); d[2] = f2bf(v.z); d[3] = f2bf(v.w);
    *(short4v*)((char*)Ax + row * 512 + ((c4f * 2) ^ ((row & 7) << 4))) = d;
  }
  __syncthreads();

  short8 af[4][8];
#pragma unroll
  for (int mf = 0; mf < 4; ++mf)
#pragma unroll
    for (int kt = 0; kt < 8; ++kt) {
      int row = mf * 16 + (lane & 15);
      int kb = kt * 64 + (lane >> 4) * 16;
      af[mf][kt] = *(const short8*)((char*)Ax + row * 512 + (kb ^ ((row & 7) << 4)));
    }

#pragma unroll 1
  for (int i = 0; i < 16; ++i) {
    short8 wfr[8];
#pragma unroll
    for (int kt = 0; kt < 8; ++kt)
      wfr[kt] = *(const short8*)(Wxp + ((((size_t)(wave * 16 + i)) * 8 + kt) * 64 + lane) * 8);
    float bv = bias[wave * 256 + i * 16 + c];
    f32x4 ac[4];
#pragma unroll
    for (int mf = 0; mf < 4; ++mf) ac[mf] = (f32x4){0.f, 0.f, 0.f, 0.f};
#pragma unroll
    for (int kt = 0; kt < 8; ++kt)
#pragma unroll
      for (int mf = 0; mf < 4; ++mf)
        ac[mf] = __builtin_amdgcn_mfma_f32_16x16x32_bf16(af[mf][kt], wfr[kt], ac[mf], 0, 0, 0);
#pragma unroll
    for (int mf = 0; mf < 4; ++mf) {
      int mrow = mb + mf * 16 + lg * 4;      // base of 4 consecutive rows
      int trel = mrow >> 8, gg = (mrow >> 2) & 63;
      uint2 pk;
      pk.x = (uint)(ushort)f2bf(ac[mf][0] + bv) |
             ((uint)(ushort)f2bf(ac[mf][1] + bv) << 16);
      pk.y = (uint)(ushort)f2bf(ac[mf][2] + bv) |
             ((uint)(ushort)f2bf(ac[mf][3] + bv) << 16);
      size_t di = (size_t)trel * TXSTEP +
                  ((((size_t)gg * 4 + wave) * 2 + (i >> 3)) * 8 + (i & 7)) * 16 + c;
      thx2[di] = pk;
    }
  }
}

// ---- Recurrent kernel: 64 WGs x 512 thr (8 waves, TRUE 2/SIMD).
// Wave = (gate, n-half): 8 ntiles x 4 kt i8 frags = 128 regs (64 VGPR + 64 AGPR).
__global__ __launch_bounds__(NTHREADS, 2) void qlstm_rec(
    const uint2* __restrict__ thx2,
    const int32x4* __restrict__ Whq,
    const float* __restrict__ sw,
    const float* __restrict__ temps,
    signed char* __restrict__ hGq, float* __restrict__ cG,
    float* __restrict__ out,
    int t0, int nsteps)
{
  __shared__ signed char A[16 * 256];   // h(t) i8, rows 0..3 real, XOR-swizzled
  __shared__ float  TH[16 * 264];       // theta f32 [chain=g*4+row][256+pad]
  __shared__ ushort ACT[16 * 264];      // activations bf16, same indexing

  const int tid = threadIdx.x;
  const int wv = tid >> 6, lane = tid & 63;
  const int g = wv >> 1, hh = wv & 1;
  const int lg = lane >> 4, c = lane & 15;
  const int bid = blockIdx.x, b0 = bid * BBLK;

  // ---- Wh frags: kt0,3 -> VGPR (builtin bookends), kt1,2 -> AGPR (asm) ----
  int32x4 w0[8], w3[8], wa1[8], wa2[8];
#pragma unroll
  for (int j = 0; j < 8; ++j) {
    const size_t nb = (size_t)(g * 16 + hh * 8 + j) * 4;
    w0[j]  = Whq[(nb + 0) * 64 + lane];
    wa1[j] = Whq[(nb + 1) * 64 + lane];
    wa2[j] = Whq[(nb + 2) * 64 + lane];
    w3[j]  = Whq[(nb + 3) * 64 + lane];
  }
  float s8[8];
#pragma unroll
  for (int j = 0; j < 8; ++j)
    s8[j] = sw[(g * 16 + hh * 8 + j) * 16 + c];

  const float invt = frcp(temps[tid >> 7]);   // act phase: gate = tid>>7
  const bool isg = ((tid >> 7) == 2);

  // ---- init A (zero + rows 0..3 from state) and c regs ----
  for (int i = tid; i < 4096; i += NTHREADS) A[i] = 0;
  __syncthreads();
  float creg0 = 0.f, creg1 = 0.f;
  if (t0 != 0) {
    if (tid < 1024) {
      int row = tid >> 8, kk = tid & 255;
      A[row * 256 + (kk ^ (row << 4))] = hGq[(size_t)(b0 + row) * 256 + kk];
    }
    creg0 = cG[(size_t)(b0 + (tid >> 8)) * 256 + (tid & 255)];
    creg1 = cG[(size_t)(b0 + (tid >> 8) + 2) * 256 + (tid & 255)];
  }
  __syncthreads();

#pragma unroll 1
  for (int ts = 0; ts < nsteps; ++ts) {
    const int t = t0 + ts;
    const bool last = (ts == nsteps - 1);

    // ---- theta_x loads (lg==0 lanes), issued first: latency hides under MFMA
    uint2 tx[8];
    if (lg == 0) {
      const uint2* tb = thx2 + (size_t)ts * TXSTEP +
                        ((((size_t)bid * 4 + g) * 2 + hh) * 8) * 16 + c;
#pragma unroll
      for (int j = 0; j < 8; ++j) tx[j] = tb[j * 16];
    }

    // ---- A-frags (i8, K=64 each) ----
    int32x4 af[4];
#pragma unroll
    for (int kt = 0; kt < 4; ++kt)
      af[kt] = *(const int32x4*)&A[c * 256 + ((kt * 64 + lg * 16) ^ ((c & 7) << 4))];

    // ---- GEMM: acc_i32 = h_i8 @ Whq^T  (32 MFMA/wave) ----
    int32x4 acc[8];
#pragma unroll
    for (int j = 0; j < 8; ++j) {
      acc[j] = (int32x4){0, 0, 0, 0};
      acc[j] = __builtin_amdgcn_mfma_i32_16x16x64_i8(af[0], w0[j], acc[j], 0, 0, 0);
    }
#pragma unroll
    for (int j = 0; j < 8; ++j) mfma_i8_a(acc[j], af[1], wa1[j]);
#pragma unroll
    for (int j = 0; j < 8; ++j) mfma_i8_a(acc[j], af[2], wa2[j]);
#pragma unroll
    for (int j = 0; j < 8; ++j)
      acc[j] = __builtin_amdgcn_mfma_i32_16x16x64_i8(af[3], w3[j], acc[j], 0, 0, 0);

    // ---- theta = theta_x + sW * acc -> TH (rows 0..3 live in lg==0 lanes) --
    if (lg == 0) {
#pragma unroll
      for (int j = 0; j < 8; ++j) {
        const int nl = (hh * 8 + j) * 16 + c;
        float x0 = u2f(tx[j].x << 16), x1 = u2f(tx[j].x & 0xffff0000u);
        float x2 = u2f(tx[j].y << 16), x3 = u2f(tx[j].y & 0xffff0000u);
        TH[(g * 4 + 0) * 264 + nl] = x0 + (float)acc[j][0] * s8[j];
        TH[(g * 4 + 1) * 264 + nl] = x1 + (float)acc[j][1] * s8[j];
        TH[(g * 4 + 2) * 264 + nl] = x2 + (float)acc[j][2] * s8[j];
        TH[(g * 4 + 3) * 264 + nl] = x3 + (float)acc[j][3] * s8[j];
      }
    }
    __syncthreads();   // B1: TH complete

    // ---- act: 16 chains x 32 threads; cos + segmented scan + activation ----
    {
      const int chain = tid >> 5, s = tid & 31;
      const float* rp = TH + chain * 264 + s * 8;
      f32x4 va = *(const f32x4*)rp;
      f32x4 vb = *(const f32x4*)(rp + 4);
      float vv[8];
      vv[0] = __cosf(va[0]); vv[1] = __cosf(va[1]);
      vv[2] = __cosf(va[2]); vv[3] = __cosf(va[3]);
      vv[4] = __cosf(vb[0]); vv[5] = __cosf(vb[1]);
      vv[6] = __cosf(vb[2]); vv[7] = __cosf(vb[3]);
      float p = vv[0];
#pragma unroll
      for (int j = 1; j < 8; ++j) p *= vv[j];
      float incl = p;
#pragma unroll
      for (int d = 1; d < 32; d <<= 1) {
        float o = __shfl_up(incl, d, 32);
        if (s >= d) incl *= o;
      }
      float run = __shfl_up(incl, 1, 32);
      if (s == 0) run = 1.f;
      short8 ob;
#pragma unroll
      for (int j = 0; j < 8; ++j) {
        run *= vv[j];
        float u = run * invt;
        ob[j] = f2bf(isg ? fast_tanh(u) : fast_sigmoid(u));
      }
      *(short8*)&ACT[chain * 264 + s * 8] = ob;
    }
    __syncthreads();   // B2: ACT ready

    // ---- update: 1024 outputs, 2 per thread ----
#pragma unroll
    for (int u = 0; u < 2; ++u) {
      const int o = tid + u * 512;
      const int row = o >> 8, kk = o & 255;
      float fv = bf2fu(ACT[(0 * 4 + row) * 264 + kk]);
      float iv = bf2fu(ACT[(1 * 4 + row) * 264 + kk]);
      float gv = bf2fu(ACT[(2 * 4 + row) * 264 + kk]);
      float ov = bf2fu(ACT[(3 * 4 + row) * 264 + kk]);
      float& cr = u ? creg1 : creg0;
      float cn = fv * cr + iv * gv;
      cr = cn;
      float h = ov * fast_tanh(cn);
      out[((size_t)t * BATCH + b0 + row) * DHID + kk] = h;
      int hq = __float2int_rn(h * 127.f);
      A[row * 256 + (kk ^ (row << 4))] = (signed char)hq;
      if (t == T_STEPS - 1) {
        out[((size_t)T_STEPS * BATCH + b0 + row) * DHID + kk] = h;
        out[((size_t)T_STEPS * BATCH + BATCH + b0 + row) * DHID + kk] = cn;
      }
      if (last) {
        hGq[(size_t)(b0 + row) * 256 + kk] = (signed char)hq;
        cG[(size_t)(b0 + row) * 256 + kk] = cn;
      }
    }
    __syncthreads();   // B3: A(t+1) complete
  }
}

extern "C" void kernel_launch(void* const* d_in, const int* in_sizes, int n_in,
                              void* d_out, int out_size, void* d_ws, size_t ws_size,
                              hipStream_t stream) {
  (void)in_sizes; (void)n_in; (void)out_size;
  const float* x   = (const float*)d_in[0];
  const float* Wf  = (const float*)d_in[1];
  const float* bf_ = (const float*)d_in[2];
  const float* tf_ = (const float*)d_in[3];
  const float* Wi  = (const float*)d_in[4];
  const float* bi_ = (const float*)d_in[5];
  const float* ti_ = (const float*)d_in[6];
  const float* Wg  = (const float*)d_in[7];
  const float* bg_ = (const float*)d_in[8];
  const float* tg_ = (const float*)d_in[9];
  const float* Wo  = (const float*)d_in[10];
  const float* bo_ = (const float*)d_in[11];
  const float* to_ = (const float*)d_in[12];

  char* ws = (char*)d_ws;
  bf16_t*      Wxp   = (bf16_t*)(ws + WS_WXP);
  signed char* Whq   = (signed char*)(ws + WS_WHQ);
  float*       sw    = (float*)(ws + WS_SW);
  float*       rq    = (float*)(ws + WS_RQ);
  float*       bias  = (float*)(ws + WS_BIAS);
  float*       temps = (float*)(ws + WS_TMP);
  signed char* hGq   = (signed char*)(ws + WS_HGQ);
  float*       cG    = (float*)(ws + WS_CG);
  uint2*       thx2  = (uint2*)(ws + WS_THX);

  size_t avail = ws_size > (size_t)(2u << 20) ? ws_size - (size_t)(2u << 20) : 0;
  int CH = 4;
  const int cands[6] = {128, 64, 32, 16, 8, 4};
  for (int ci = 0; ci < 6; ++ci)
    if ((size_t)cands[ci] * 512 * 1024 <= avail) { CH = cands[ci]; break; }

  hipLaunchKernelGGL(k_scales, dim3(4), dim3(256), 0, stream,
                     Wf, Wi, Wg, Wo, sw, rq);
  hipLaunchKernelGGL(k_packx, dim3(128), dim3(256), 0, stream,
                     Wf, Wi, Wg, Wo, bf_, bi_, bg_, bo_, tf_, ti_, tg_, to_,
                     Wxp, bias, temps);
  hipLaunchKernelGGL(k_packh, dim3(64), dim3(256), 0, stream,
                     Wf, Wi, Wg, Wo, rq, Whq);

  for (int c0 = 0; c0 < T_STEPS; c0 += CH) {
    hipLaunchKernelGGL(gemm_thx, dim3(CH * 4), dim3(256), 0, stream,
                       x + (size_t)c0 * BATCH * DIN, Wxp, bias, thx2);
    hipLaunchKernelGGL(qlstm_rec, dim3(NWG), dim3(NTHREADS), 0, stream,
                       thx2, (const int32x4*)Whq, sw, temps, hGq, cG,
                       (float*)d_out, c0, CH);
  }
}

// Round 10
// 1426.443 us; speedup vs baseline: 2.9638x; 1.0382x over previous
//
#include <hip/hip_runtime.h>

#define T_STEPS 512
#define BATCH   256
#define DIN     256
#define DHID    256
#define BBLK    2        // batch rows per WG
#define NWG     128      // BATCH / BBLK
#define NTHREADS 512     // 8 waves: wave = (gate, n-half), 2 waves/SIMD

typedef short bf16_t;
typedef __attribute__((ext_vector_type(4))) short short4v;
typedef __attribute__((ext_vector_type(8))) short short8;
typedef __attribute__((ext_vector_type(4))) float f32x4;
typedef __attribute__((ext_vector_type(4))) int int32x4;
typedef unsigned int uint;
typedef unsigned short ushort;

// ---- workspace layout (bytes) ----
#define WS_WXP  0u                   // 512 KB bf16 Wx frags
#define WS_WHQ  (512u << 10)         // 256 KB i8 Wh frags
#define WS_SW   (768u << 10)         // 4 KB f32 sW[1024] (amax/127^2)
#define WS_RQ   (772u << 10)         // 4 KB f32 rq[1024] (127/amax)
#define WS_BIAS (776u << 10)         // 4 KB
#define WS_TMP  (780u << 10)         // 16 B
#define WS_HGQ  (784u << 10)         // 64 KB i8 h state [256][256]
#define WS_CG   (848u << 10)         // 256 KB f32 c state
#define WS_THX  (2u << 20)           // CH*512KB theta_x chunk

#define TXSTEP  131072               // uints per t: 128 row-pairs x 1024

__device__ inline short f2bf(float f) {
  union { float f; uint u; } v; v.f = f;
  uint r = (v.u + 0x7FFFu + ((v.u >> 16) & 1u)) >> 16;
  return (short)r;
}
__device__ inline float bf2fu(ushort s) {
  union { float f; uint u; } v; v.u = ((uint)s) << 16;
  return v.f;
}
__device__ inline float u2f(uint u) {
  union { float f; uint u; } v; v.u = u; return v.f;
}
__device__ inline float frcp(float x) { return __builtin_amdgcn_rcpf(x); }
__device__ inline float fast_sigmoid(float x) { return frcp(1.f + __expf(-x)); }
__device__ inline float fast_tanh(float x) {
  float ax = fabsf(x);
  float e = __expf(2.f * ax);              // inf-safe
  float r = 1.f - 2.f * frcp(e + 1.f);
  return copysignf(r, x);
}

// asm i8 MFMA with B operand pinned in AGPRs (r5/r7/r9-proven pattern:
// chains bookended by builtins so the compiler guards VALU<->MFMA hazards).
__device__ inline void mfma_i8_a(int32x4& acc, int32x4 a, int32x4 b) {
  asm("v_mfma_i32_16x16x64_i8 %0, %1, %2, %0"
      : "+v"(acc) : "v"(a), "a"(b));
}

// ---- per-row amax scales for Wh (k in [256,512)) ----
// sw = amax / 127^2: dequant for BOTH W (x127/amax) and h (x127) quant steps.
__global__ __launch_bounds__(256) void k_scales(
    const float* __restrict__ Wf, const float* __restrict__ Wi,
    const float* __restrict__ Wg, const float* __restrict__ Wo,
    float* __restrict__ sw, float* __restrict__ rq)
{
  int n = blockIdx.x * 256 + threadIdx.x;       // 0..1023
  int gate = n >> 8, nrow = n & 255;
  const float* W = gate == 0 ? Wf : gate == 1 ? Wi : gate == 2 ? Wg : Wo;
  const float4* row = (const float4*)(W + (size_t)nrow * 512 + 256);
  float amax = 0.f;
#pragma unroll 4
  for (int k = 0; k < 64; ++k) {
    float4 v = row[k];
    amax = fmaxf(amax, fmaxf(fmaxf(fabsf(v.x), fabsf(v.y)),
                             fmaxf(fabsf(v.z), fabsf(v.w))));
  }
  sw[n] = amax / (127.f * 127.f);
  rq[n] = amax > 0.f ? 127.f / amax : 0.f;
}

// ---- pack Wx (k<256) into bf16 MFMA B-frag order + bias + temps ----
__global__ __launch_bounds__(256) void k_packx(
    const float* __restrict__ Wf, const float* __restrict__ Wi,
    const float* __restrict__ Wg, const float* __restrict__ Wo,
    const float* __restrict__ bf_, const float* __restrict__ bi_,
    const float* __restrict__ bg_, const float* __restrict__ bo_,
    const float* __restrict__ tf_, const float* __restrict__ ti_,
    const float* __restrict__ tg_, const float* __restrict__ to_,
    bf16_t* __restrict__ Wxp, float* __restrict__ bias,
    float* __restrict__ temps)
{
  int tid = blockIdx.x * 256 + threadIdx.x;     // 0..32767
  int nt = tid >> 9;
  int kt = (tid >> 6) & 7;
  int lane = tid & 63;
  int n = nt * 16 + (lane & 15);
  int gate = n >> 8, nrow = n & 255;
  int k = kt * 32 + (lane >> 4) * 8;
  const float* W = gate == 0 ? Wf : gate == 1 ? Wi : gate == 2 ? Wg : Wo;
  const float* src = W + (size_t)nrow * 512 + k;
  short8 d;
#pragma unroll
  for (int j = 0; j < 8; ++j) d[j] = f2bf(src[j]);
  *(short8*)(Wxp + (size_t)tid * 8) = d;

  if (tid < 1024) {
    int g2 = tid >> 8;
    const float* bs = g2 == 0 ? bf_ : g2 == 1 ? bi_ : g2 == 2 ? bg_ : bo_;
    bias[tid] = bs[tid & 255];
  }
  if (tid < 4) {
    const float* ts = tid == 0 ? tf_ : tid == 1 ? ti_ : tid == 2 ? tg_ : to_;
    temps[tid] = ts[0];
  }
}

// ---- pack Wh (k in [256,512)) into i8 16x16x64 B-frag order ----
__global__ __launch_bounds__(256) void k_packh(
    const float* __restrict__ Wf, const float* __restrict__ Wi,
    const float* __restrict__ Wg, const float* __restrict__ Wo,
    const float* __restrict__ rq, signed char* __restrict__ Whq)
{
  int tid = blockIdx.x * 256 + threadIdx.x;     // 0..16383
  int nt = tid >> 8;
  int kt = (tid >> 6) & 3;
  int lane = tid & 63;
  int n = nt * 16 + (lane & 15);
  int gate = n >> 8, nrow = n & 255;
  int k0 = 256 + kt * 64 + (lane >> 4) * 16;
  const float* W = gate == 0 ? Wf : gate == 1 ? Wi : gate == 2 ? Wg : Wo;
  const float* src = W + (size_t)nrow * 512 + k0;
  float r = rq[n];
  union { signed char b[16]; int32x4 v; } pk;
#pragma unroll
  for (int j = 0; j < 16; ++j) {
    int qi = __float2int_rn(src[j] * r);
    qi = qi > 127 ? 127 : (qi < -127 ? -127 : qi);
    pk.b[j] = (signed char)qi;
  }
  *(int32x4*)(Whq + (size_t)tid * 16) = pk.v;
}

// ---- theta_x GEMM; store layout: uint[rowpair][g][hh][j][c], rowpair
//      global (incl t): uint = 2 bf16 (rows 2p, 2p+1) of col n=(g*16+hh*8+j)*16+c.
__global__ __launch_bounds__(256, 1) void gemm_thx(
    const float* __restrict__ x,        // chunk slice [CH*256, 256]
    const bf16_t* __restrict__ Wxp,
    const float* __restrict__ bias,
    uint* __restrict__ thxU)
{
  __shared__ bf16_t Ax[64 * 256];       // XOR-swizzled, 512 B row stride
  const int tid = threadIdx.x;
  const int wave = tid >> 6, lane = tid & 63;
  const int lg = lane >> 4, c = lane & 15;
  const int mb = blockIdx.x * 64;

#pragma unroll
  for (int rep = 0; rep < 16; ++rep) {
    int idx = tid + rep * 256;
    int row = idx >> 6, c4f = (idx & 63) * 4;
    float4 v = *(const float4*)(x + (size_t)(mb + row) * 256 + c4f);
    short4v d;
    d[0] = f2bf(v.x); d[1] = f2bf(v.y); d[2] = f2bf(v.z); d[3] = f2bf(v.w);
    *(short4v*)((char*)Ax + row * 512 + ((c4f * 2) ^ ((row & 7) << 4))) = d;
  }
  __syncthreads();

  short8 af[4][8];
#pragma unroll
  for (int mf = 0; mf < 4; ++mf)
#pragma unroll
    for (int kt = 0; kt < 8; ++kt) {
      int row = mf * 16 + (lane & 15);
      int kb = kt * 64 + (lane >> 4) * 16;
      af[mf][kt] = *(const short8*)((char*)Ax + row * 512 + (kb ^ ((row & 7) << 4)));
    }

#pragma unroll 1
  for (int i = 0; i < 16; ++i) {
    short8 wfr[8];
#pragma unroll
    for (int kt = 0; kt < 8; ++kt)
      wfr[kt] = *(const short8*)(Wxp + ((((size_t)(wave * 16 + i)) * 8 + kt) * 64 + lane) * 8);
    float bv = bias[wave * 256 + i * 16 + c];
    f32x4 ac[4];
#pragma unroll
    for (int mf = 0; mf < 4; ++mf) ac[mf] = (f32x4){0.f, 0.f, 0.f, 0.f};
#pragma unroll
    for (int kt = 0; kt < 8; ++kt)
#pragma unroll
      for (int mf = 0; mf < 4; ++mf)
        ac[mf] = __builtin_amdgcn_mfma_f32_16x16x32_bf16(af[mf][kt], wfr[kt], ac[mf], 0, 0, 0);
    const int hh = i >> 3, j = i & 7;
    const size_t off = (size_t)(((wave * 2 + hh) * 8 + j) * 16 + c);
#pragma unroll
    for (int mf = 0; mf < 4; ++mf) {
      int mrow = mb + mf * 16 + lg * 4;      // multiple of 4
      size_t p0 = (size_t)(mrow >> 1);       // row-pair of rows +0,+1
      uint pk0 = (uint)(ushort)f2bf(ac[mf][0] + bv) |
                 ((uint)(ushort)f2bf(ac[mf][1] + bv) << 16);
      uint pk1 = (uint)(ushort)f2bf(ac[mf][2] + bv) |
                 ((uint)(ushort)f2bf(ac[mf][3] + bv) << 16);
      thxU[p0 * 1024 + off] = pk0;
      thxU[(p0 + 1) * 1024 + off] = pk1;
    }
  }
}

// ---- Recurrent kernel: 128 WGs x 512 thr (8 waves, 2/SIMD).
// Wave = (gate, n-half). Batch rows replicated at A-rows {0,4}=b0, {8,12}=b1
// so every lg-group's reg0 holds a real row -> epilogue uses all 64 lanes.
__global__ __launch_bounds__(NTHREADS, 2) void qlstm_rec(
    const uint* __restrict__ thxU,
    const int32x4* __restrict__ Whq,
    const float* __restrict__ sw,
    const float* __restrict__ temps,
    signed char* __restrict__ hGq, float* __restrict__ cG,
    float* __restrict__ out,
    int t0, int nsteps)
{
  __shared__ signed char A[16 * 256];   // h(t) i8, rows 0,4,8,12 real
  __shared__ float  TH[8 * 264];        // theta f32 [chain=g*2+b][256+pad]
  __shared__ ushort ACT[8 * 264];       // activations bf16, same indexing

  const int tid = threadIdx.x;
  const int wv = tid >> 6, lane = tid & 63;
  const int g = wv >> 1, hh = wv & 1;
  const int lg = lane >> 4, c = lane & 15;
  const int bsel = lg >> 1;             // batch row this lane epilogues
  const int jbase = (lg & 1) * 4;       // j-subset {0-3} or {4-7}
  const int bid = blockIdx.x, b0 = bid * BBLK;

  // ---- Wh frags: kt0,3 -> VGPR (builtin bookends), kt1,2 -> AGPR (asm) ----
  int32x4 w0[8], w3[8], wa1[8], wa2[8];
#pragma unroll
  for (int j = 0; j < 8; ++j) {
    const size_t nb = (size_t)(g * 16 + hh * 8 + j) * 4;
    w0[j]  = Whq[(nb + 0) * 64 + lane];
    wa1[j] = Whq[(nb + 1) * 64 + lane];
    wa2[j] = Whq[(nb + 2) * 64 + lane];
    w3[j]  = Whq[(nb + 3) * 64 + lane];
  }
  float s8[4];
#pragma unroll
  for (int jp = 0; jp < 4; ++jp)
    s8[jp] = sw[(g * 16 + hh * 8 + jbase + jp) * 16 + c];

  const float invt = frcp(temps[g]);    // act phase: wave wv = chain (g, hh)
  const bool isg = (g == 2);

  // ---- init A (rows b*8, b*8+4) and c reg; thread = (row=tid>>8, kk) ----
  const int urow = tid >> 8, ukk = tid & 255;
  float creg = 0.f;
  {
    signed char hv = 0;
    if (t0 != 0) {
      hv = hGq[(size_t)(b0 + urow) * 256 + ukk];
      creg = cG[(size_t)(b0 + urow) * 256 + ukk];
    }
    const int r0 = urow * 8, r1 = urow * 8 + 4;
    A[r0 * 256 + (ukk ^ ((r0 & 7) << 4))] = hv;
    A[r1 * 256 + (ukk ^ ((r1 & 7) << 4))] = hv;
  }
  __syncthreads();

  // ---- theta_x: 4 uints per lane per step, prefetched 1 step ahead ----
  const size_t joff = (size_t)(((g * 2 + hh) * 8 + jbase) * 16 + c);
  uint tx[4], txn[4];
  {
    const uint* tb = thxU + (size_t)bid * 1024 + joff;   // ts = 0
#pragma unroll
    for (int jp = 0; jp < 4; ++jp) tx[jp] = tb[jp * 16];
  }

#pragma unroll 1
  for (int ts = 0; ts < nsteps; ++ts) {
    const int t = t0 + ts;
    const bool last = (ts == nsteps - 1);

    // ---- 1. prefetch theta_x(ts+1): consumed next iteration ----
    {
      const int tsn = (ts + 1 < nsteps) ? ts + 1 : ts;
      const uint* tb = thxU + ((size_t)tsn * 128 + bid) * 1024 + joff;
#pragma unroll
      for (int jp = 0; jp < 4; ++jp) txn[jp] = tb[jp * 16];
    }

    // ---- 2. A-frags (i8, K=64 each) ----
    int32x4 af[4];
#pragma unroll
    for (int kt = 0; kt < 4; ++kt)
      af[kt] = *(const int32x4*)&A[c * 256 + ((kt * 64 + lg * 16) ^ ((c & 7) << 4))];

    // ---- 3. GEMM: acc_i32 = h_i8 @ Whq^T  (32 MFMA/wave) ----
    int32x4 acc[8];
#pragma unroll
    for (int j = 0; j < 8; ++j) {
      acc[j] = (int32x4){0, 0, 0, 0};
      acc[j] = __builtin_amdgcn_mfma_i32_16x16x64_i8(af[0], w0[j], acc[j], 0, 0, 0);
    }
#pragma unroll
    for (int j = 0; j < 8; ++j) mfma_i8_a(acc[j], af[1], wa1[j]);
#pragma unroll
    for (int j = 0; j < 8; ++j) mfma_i8_a(acc[j], af[2], wa2[j]);
#pragma unroll
    for (int j = 0; j < 8; ++j)
      acc[j] = __builtin_amdgcn_mfma_i32_16x16x64_i8(af[3], w3[j], acc[j], 0, 0, 0);

    // ---- 4. theta = theta_x + sW*acc -> TH; ALL 64 lanes, 4 stores each ----
    // lane (lg,c): batch row bsel lives in acc[*][0]; j-subset jbase..jbase+3
    {
      const int chain = g * 2 + bsel;
#pragma unroll
      for (int jp = 0; jp < 4; ++jp) {
        const int jj = jbase + jp;
        uint w = tx[jp];
        float xv = bsel ? u2f(w & 0xffff0000u) : u2f(w << 16);
        TH[chain * 264 + hh * 128 + jj * 16 + c] =
            xv + (float)acc[jj][0] * s8[jp];
      }
    }
    __syncthreads();   // B1: TH complete

    // ---- 5. act: wave wv owns chain wv; 4 elems/lane, width-64 scan ----
    {
      f32x4 v = *(const f32x4*)&TH[wv * 264 + lane * 4];
      float vv0 = __cosf(v[0]), vv1 = __cosf(v[1]);
      float vv2 = __cosf(v[2]), vv3 = __cosf(v[3]);
      float p = vv0 * vv1 * vv2 * vv3;
      float incl = p;
#pragma unroll
      for (int d = 1; d < 64; d <<= 1) {
        float o = __shfl_up(incl, d);
        if (lane >= d) incl *= o;
      }
      float run = __shfl_up(incl, 1);
      if (lane == 0) run = 1.f;
      short4v ob;
      run *= vv0; ob[0] = f2bf(isg ? fast_tanh(run * invt) : fast_sigmoid(run * invt));
      run *= vv1; ob[1] = f2bf(isg ? fast_tanh(run * invt) : fast_sigmoid(run * invt));
      run *= vv2; ob[2] = f2bf(isg ? fast_tanh(run * invt) : fast_sigmoid(run * invt));
      run *= vv3; ob[3] = f2bf(isg ? fast_tanh(run * invt) : fast_sigmoid(run * invt));
      *(short4v*)&ACT[wv * 264 + lane * 4] = ob;
    }
    __syncthreads();   // B2: ACT ready

    // ---- 6. update: 512 outputs, 1 per thread ----
    {
      float fv = bf2fu(ACT[(0 * 2 + urow) * 264 + ukk]);
      float iv = bf2fu(ACT[(1 * 2 + urow) * 264 + ukk]);
      float gv = bf2fu(ACT[(2 * 2 + urow) * 264 + ukk]);
      float ov = bf2fu(ACT[(3 * 2 + urow) * 264 + ukk]);
      float cn = fv * creg + iv * gv;
      creg = cn;
      float h = ov * fast_tanh(cn);
      out[((size_t)t * BATCH + b0 + urow) * DHID + ukk] = h;
      int hq = __float2int_rn(h * 127.f);
      const int r0 = urow * 8, r1 = urow * 8 + 4;
      A[r0 * 256 + (ukk ^ ((r0 & 7) << 4))] = (signed char)hq;
      A[r1 * 256 + (ukk ^ ((r1 & 7) << 4))] = (signed char)hq;
      if (t == T_STEPS - 1) {
        out[((size_t)T_STEPS * BATCH + b0 + urow) * DHID + ukk] = h;
        out[((size_t)T_STEPS * BATCH + BATCH + b0 + urow) * DHID + ukk] = cn;
      }
      if (last) {
        hGq[(size_t)(b0 + urow) * 256 + ukk] = (signed char)hq;
        cG[(size_t)(b0 + urow) * 256 + ukk] = cn;
      }
    }
    __syncthreads();   // B3: A(t+1) complete

#pragma unroll
    for (int jp = 0; jp < 4; ++jp) tx[jp] = txn[jp];
  }
}

extern "C" void kernel_launch(void* const* d_in, const int* in_sizes, int n_in,
                              void* d_out, int out_size, void* d_ws, size_t ws_size,
                              hipStream_t stream) {
  (void)in_sizes; (void)n_in; (void)out_size;
  const float* x   = (const float*)d_in[0];
  const float* Wf  = (const float*)d_in[1];
  const float* bf_ = (const float*)d_in[2];
  const float* tf_ = (const float*)d_in[3];
  const float* Wi  = (const float*)d_in[4];
  const float* bi_ = (const float*)d_in[5];
  const float* ti_ = (const float*)d_in[6];
  const float* Wg  = (const float*)d_in[7];
  const float* bg_ = (const float*)d_in[8];
  const float* tg_ = (const float*)d_in[9];
  const float* Wo  = (const float*)d_in[10];
  const float* bo_ = (const float*)d_in[11];
  const float* to_ = (const float*)d_in[12];

  char* ws = (char*)d_ws;
  bf16_t*      Wxp   = (bf16_t*)(ws + WS_WXP);
  signed char* Whq   = (signed char*)(ws + WS_WHQ);
  float*       sw    = (float*)(ws + WS_SW);
  float*       rq    = (float*)(ws + WS_RQ);
  float*       bias  = (float*)(ws + WS_BIAS);
  float*       temps = (float*)(ws + WS_TMP);
  signed char* hGq   = (signed char*)(ws + WS_HGQ);
  float*       cG    = (float*)(ws + WS_CG);
  uint*        thxU  = (uint*)(ws + WS_THX);

  size_t avail = ws_size > (size_t)(2u << 20) ? ws_size - (size_t)(2u << 20) : 0;
  int CH = 4;
  const int cands[6] = {128, 64, 32, 16, 8, 4};
  for (int ci = 0; ci < 6; ++ci)
    if ((size_t)cands[ci] * 512 * 1024 <= avail) { CH = cands[ci]; break; }

  hipLaunchKernelGGL(k_scales, dim3(4), dim3(256), 0, stream,
                     Wf, Wi, Wg, Wo, sw, rq);
  hipLaunchKernelGGL(k_packx, dim3(128), dim3(256), 0, stream,
                     Wf, Wi, Wg, Wo, bf_, bi_, bg_, bo_, tf_, ti_, tg_, to_,
                     Wxp, bias, temps);
  hipLaunchKernelGGL(k_packh, dim3(64), dim3(256), 0, stream,
                     Wf, Wi, Wg, Wo, rq, Whq);

  for (int c0 = 0; c0 < T_STEPS; c0 += CH) {
    hipLaunchKernelGGL(gemm_thx, dim3(CH * 4), dim3(256), 0, stream,
                       x + (size_t)c0 * BATCH * DIN, Wxp, bias, thxU);
    hipLaunchKernelGGL(qlstm_rec, dim3(NWG), dim3(NTHREADS), 0, stream,
                       thxU, (const int32x4*)Whq, sw, temps, hGq, cG,
                       (float*)d_out, c0, CH);
  }
}

// Round 11
// 991.375 us; speedup vs baseline: 4.2644x; 1.4389x over previous
//
#include <hip/hip_runtime.h>

#define T_STEPS 512
#define BATCH   256
#define DIN     256
#define DHID    256
#define NWG     256      // one WG per batch row
#define NTHREADS 512     // 8 waves: wave = (gate, n-half), 2 waves/SIMD

typedef short bf16_t;
typedef __attribute__((ext_vector_type(4))) short short4v;
typedef __attribute__((ext_vector_type(8))) short short8;
typedef __attribute__((ext_vector_type(4))) float f32x4;
typedef __attribute__((ext_vector_type(4))) int int32x4;
typedef unsigned int uint;
typedef unsigned short ushort;

// ---- workspace layout (bytes) ----
#define WS_WXP  0u                   // 512 KB bf16 Wx frags
#define WS_WHQ  (512u << 10)         // 256 KB i8 Wh frags
#define WS_SW   (768u << 10)         // 4 KB f32 sW[1024] (amax/127^2)
#define WS_RQ   (772u << 10)         // 4 KB f32 rq[1024] (127/amax)
#define WS_BIAS (776u << 10)         // 4 KB
#define WS_TMP  (780u << 10)         // 16 B
#define WS_HGQ  (784u << 10)         // 64 KB i8 h state [256][256]
#define WS_CG   (848u << 10)         // 256 KB f32 c state
#define WS_THX  (2u << 20)           // CH*512KB theta_x chunk

#define TXSTEPU 131072               // uints per t: 256 rows x 4 gates x 128

__device__ inline short f2bf(float f) {
  union { float f; uint u; } v; v.f = f;
  uint r = (v.u + 0x7FFFu + ((v.u >> 16) & 1u)) >> 16;
  return (short)r;
}
__device__ inline float bf2fu(ushort s) {
  union { float f; uint u; } v; v.u = ((uint)s) << 16;
  return v.f;
}
__device__ inline float u2f(uint u) {
  union { float f; uint u; } v; v.u = u; return v.f;
}
__device__ inline float frcp(float x) { return __builtin_amdgcn_rcpf(x); }
__device__ inline float fast_sigmoid(float x) { return frcp(1.f + __expf(-x)); }
__device__ inline float fast_tanh(float x) {
  float ax = fabsf(x);
  float e = __expf(2.f * ax);              // inf-safe
  float r = 1.f - 2.f * frcp(e + 1.f);
  return copysignf(r, x);
}

// asm i8 MFMA with B pinned in AGPRs (r5/r7/r9/r10-proven: chains bookended
// by builtins so the compiler guards VALU<->MFMA hazards).
__device__ inline void mfma_i8_a(int32x4& acc, int32x4 a, int32x4 b) {
  asm("v_mfma_i32_16x16x64_i8 %0, %1, %2, %0"
      : "+v"(acc) : "v"(a), "a"(b));
}

// ---- per-neuron amax scales for Wh (k in [256,512)) ----
__global__ __launch_bounds__(256) void k_scales(
    const float* __restrict__ Wf, const float* __restrict__ Wi,
    const float* __restrict__ Wg, const float* __restrict__ Wo,
    float* __restrict__ sw, float* __restrict__ rq)
{
  int n = blockIdx.x * 256 + threadIdx.x;       // 0..1023
  int gate = n >> 8, nrow = n & 255;
  const float* W = gate == 0 ? Wf : gate == 1 ? Wi : gate == 2 ? Wg : Wo;
  const float4* row = (const float4*)(W + (size_t)nrow * 512 + 256);
  float amax = 0.f;
#pragma unroll 4
  for (int k = 0; k < 64; ++k) {
    float4 v = row[k];
    amax = fmaxf(amax, fmaxf(fmaxf(fabsf(v.x), fabsf(v.y)),
                             fmaxf(fabsf(v.z), fabsf(v.w))));
  }
  sw[n] = amax / (127.f * 127.f);
  rq[n] = amax > 0.f ? 127.f / amax : 0.f;
}

// ---- pack Wx (k<256) into bf16 MFMA B-frag order + bias + temps ----
__global__ __launch_bounds__(256) void k_packx(
    const float* __restrict__ Wf, const float* __restrict__ Wi,
    const float* __restrict__ Wg, const float* __restrict__ Wo,
    const float* __restrict__ bf_, const float* __restrict__ bi_,
    const float* __restrict__ bg_, const float* __restrict__ bo_,
    const float* __restrict__ tf_, const float* __restrict__ ti_,
    const float* __restrict__ tg_, const float* __restrict__ to_,
    bf16_t* __restrict__ Wxp, float* __restrict__ bias,
    float* __restrict__ temps)
{
  int tid = blockIdx.x * 256 + threadIdx.x;     // 0..32767
  int nt = tid >> 9;
  int kt = (tid >> 6) & 7;
  int lane = tid & 63;
  int n = nt * 16 + (lane & 15);
  int gate = n >> 8, nrow = n & 255;
  int k = kt * 32 + (lane >> 4) * 8;
  const float* W = gate == 0 ? Wf : gate == 1 ? Wi : gate == 2 ? Wg : Wo;
  const float* src = W + (size_t)nrow * 512 + k;
  short8 d;
#pragma unroll
  for (int j = 0; j < 8; ++j) d[j] = f2bf(src[j]);
  *(short8*)(Wxp + (size_t)tid * 8) = d;

  if (tid < 1024) {
    int g2 = tid >> 8;
    const float* bs = g2 == 0 ? bf_ : g2 == 1 ? bi_ : g2 == 2 ? bg_ : bo_;
    bias[tid] = bs[tid & 255];
  }
  if (tid < 4) {
    const float* ts = tid == 0 ? tf_ : tid == 1 ? ti_ : tid == 2 ? tg_ : to_;
    temps[tid] = ts[0];
  }
}

// ---- pack Wh into i8 16x16x64 B-frag order with scan-friendly n-perm ----
// ntile nt = g*16 + hh*8 + j, frag col fc: neuron kk(within gate) =
// hh*128 + (j>>1)*32 + fc*2 + (j&1)  -> rec lane L holds kk pair {2L, 2L+1}.
__global__ __launch_bounds__(256) void k_packh(
    const float* __restrict__ Wf, const float* __restrict__ Wi,
    const float* __restrict__ Wg, const float* __restrict__ Wo,
    const float* __restrict__ rq, signed char* __restrict__ Whq)
{
  int tid = blockIdx.x * 256 + threadIdx.x;     // 0..16383
  int nt = tid >> 8;
  int kt = (tid >> 6) & 3;
  int lane = tid & 63;
  int fc = lane & 15;
  int gate = nt >> 4, hh = (nt >> 3) & 1, j = nt & 7;
  int n = gate * 256 + hh * 128 + ((j >> 1) << 5) + fc * 2 + (j & 1);
  int nrow = n & 255;
  int k0 = 256 + kt * 64 + (lane >> 4) * 16;
  const float* W = gate == 0 ? Wf : gate == 1 ? Wi : gate == 2 ? Wg : Wo;
  const float* src = W + (size_t)nrow * 512 + k0;
  float r = rq[n];
  union { signed char b[16]; int32x4 v; } pk;
#pragma unroll
  for (int jj = 0; jj < 16; ++jj) {
    int qi = __float2int_rn(src[jj] * r);
    qi = qi > 127 ? 127 : (qi < -127 ? -127 : qi);
    pk.b[jj] = (signed char)qi;
  }
  *(int32x4*)(Whq + (size_t)tid * 16) = pk.v;
}

// ---- theta_x GEMM; store ushort[t][row256][gate4][kk256] (kk linear) ----
__global__ __launch_bounds__(256, 1) void gemm_thx(
    const float* __restrict__ x,        // chunk slice [CH*256, 256]
    const bf16_t* __restrict__ Wxp,
    const float* __restrict__ bias,
    ushort* __restrict__ thxH)
{
  __shared__ bf16_t Ax[64 * 256];       // XOR-swizzled, 512 B row stride
  const int tid = threadIdx.x;
  const int wave = tid >> 6, lane = tid & 63;
  const int lg = lane >> 4, c = lane & 15;
  const int mb = blockIdx.x * 64;

#pragma unroll
  for (int rep = 0; rep < 16; ++rep) {
    int idx = tid + rep * 256;
    int row = idx >> 6, c4f = (idx & 63) * 4;
    float4 v = *(const float4*)(x + (size_t)(mb + row) * 256 + c4f);
    short4v d;
    d[0] = f2bf(v.x); d[1] = f2bf(v.y); d[2] = f2bf(v.z); d[3] = f2bf(v.w);
    *(short4v*)((char*)Ax + row * 512 + ((c4f * 2) ^ ((row & 7) << 4))) = d;
  }
  __syncthreads();

  short8 af[4][8];
#pragma unroll
  for (int mf = 0; mf < 4; ++mf)
#pragma unroll
    for (int kt = 0; kt < 8; ++kt) {
      int row = mf * 16 + (lane & 15);
      int kb = kt * 64 + (lane >> 4) * 16;
      af[mf][kt] = *(const short8*)((char*)Ax + row * 512 + (kb ^ ((row & 7) << 4)));
    }

#pragma unroll 1
  for (int i = 0; i < 16; ++i) {
    short8 wfr[8];
#pragma unroll
    for (int kt = 0; kt < 8; ++kt)
      wfr[kt] = *(const short8*)(Wxp + ((((size_t)(wave * 16 + i)) * 8 + kt) * 64 + lane) * 8);
    float bv = bias[wave * 256 + i * 16 + c];
    f32x4 ac[4];
#pragma unroll
    for (int mf = 0; mf < 4; ++mf) ac[mf] = (f32x4){0.f, 0.f, 0.f, 0.f};
#pragma unroll
    for (int kt = 0; kt < 8; ++kt)
#pragma unroll
      for (int mf = 0; mf < 4; ++mf)
        ac[mf] = __builtin_amdgcn_mfma_f32_16x16x32_bf16(af[mf][kt], wfr[kt], ac[mf], 0, 0, 0);
    const int kkg = i * 16 + c;
#pragma unroll
    for (int mf = 0; mf < 4; ++mf)
#pragma unroll
      for (int r = 0; r < 4; ++r) {
        int mrow = mb + mf * 16 + lg * 4 + r;
        int trel = mrow >> 8, rw = mrow & 255;
        thxH[(((size_t)trel * 256 + rw) * 4 + wave) * 256 + kkg] =
            (ushort)f2bf(ac[mf][r] + bv);
      }
  }
}

// ---- Recurrent kernel: 256 WGs (1 row each) x 512 thr, 2 waves/SIMD.
// Wave (g,hh): 8 ntiles x 4 kt i8 frags. In-register dequant + cos +
// width-64 shfl scan; only halfTot(4 floats) + ACT cross LDS.
__global__ __launch_bounds__(NTHREADS, 2) void qlstm_rec(
    const uint* __restrict__ thxU,
    const int32x4* __restrict__ Whq,
    const float* __restrict__ sw,
    const float* __restrict__ temps,
    signed char* __restrict__ hGq, float* __restrict__ cG,
    float* __restrict__ out,
    int t0, int nsteps)
{
  __shared__ signed char A[16 * 256];   // h(t) i8 at rows 0,4,8,12 (replicas)
  __shared__ ushort ACT[4 * 264];       // activations bf16 [gate][kk]
  __shared__ float halfTot[4];

  const int tid = threadIdx.x;
  const int wv = tid >> 6, lane = tid & 63;
  const int g = wv >> 1, hh = wv & 1;
  const int lg = lane >> 4, c = lane & 15;
  const int row = blockIdx.x;

  // ---- Wh frags: kt0,3 -> VGPR (builtin bookends), kt1,2 -> AGPR (asm) ----
  int32x4 w0[8], w3[8], wa1[8], wa2[8];
#pragma unroll
  for (int j = 0; j < 8; ++j) {
    const size_t nb = (size_t)(g * 16 + hh * 8 + j) * 4;
    w0[j]  = Whq[(nb + 0) * 64 + lane];
    wa1[j] = Whq[(nb + 1) * 64 + lane];
    wa2[j] = Whq[(nb + 2) * 64 + lane];
    w3[j]  = Whq[(nb + 3) * 64 + lane];
  }
  // scales: s8j[j] = sw[g*256 + hh*128 + (j>>1)*32 + c*2 + (j&1)]
  float s8j[8];
#pragma unroll
  for (int q = 0; q < 4; ++q) {
    float2 sv = *(const float2*)&sw[g * 256 + hh * 128 + q * 32 + c * 2];
    s8j[2 * q] = sv.x; s8j[2 * q + 1] = sv.y;
  }

  const float invt = frcp(temps[g]);
  const bool isg = (g == 2);

  // ---- init h/c: thread = (e=tid>>8 replica pair, ukk) ----
  const int e = tid >> 8, ukk = tid & 255;
  float creg = 0.f;
  {
    signed char hv = 0;
    if (t0 != 0) {
      hv = hGq[(size_t)row * 256 + ukk];
      creg = cG[(size_t)row * 256 + ukk];
    }
    const int r0 = e * 4, r1 = e * 4 + 8;
    A[r0 * 256 + (ukk ^ ((r0 & 7) << 4))] = hv;
    A[r1 * 256 + (ukk ^ ((r1 & 7) << 4))] = hv;
  }
  __syncthreads();

  // theta_x: 1 uint (2 bf16) per lane per step, prefetched 1 ahead
  const size_t txbase = (((size_t)row * 4 + g) * 128) + hh * 64 + lane;
  uint tx = thxU[txbase];

#pragma unroll 1
  for (int ts = 0; ts < nsteps; ++ts) {
    const int t = t0 + ts;
    const bool last = (ts == nsteps - 1);

    // prefetch theta_x(ts+1)
    const int tsn = (ts + 1 < nsteps) ? ts + 1 : ts;
    const uint txn = thxU[(size_t)tsn * TXSTEPU + txbase];

    // A-frags (i8, K=64 each)
    int32x4 af[4];
#pragma unroll
    for (int kt = 0; kt < 4; ++kt)
      af[kt] = *(const int32x4*)&A[c * 256 + ((kt * 64 + lg * 16) ^ ((c & 7) << 4))];

    // GEMM: acc_i32 = h_i8 @ Whq^T (32 MFMA/wave)
    int32x4 acc[8];
#pragma unroll
    for (int j = 0; j < 8; ++j) {
      acc[j] = (int32x4){0, 0, 0, 0};
      acc[j] = __builtin_amdgcn_mfma_i32_16x16x64_i8(af[0], w0[j], acc[j], 0, 0, 0);
    }
#pragma unroll
    for (int j = 0; j < 8; ++j) mfma_i8_a(acc[j], af[1], wa1[j]);
#pragma unroll
    for (int j = 0; j < 8; ++j) mfma_i8_a(acc[j], af[2], wa2[j]);
#pragma unroll
    for (int j = 0; j < 8; ++j)
      acc[j] = __builtin_amdgcn_mfma_i32_16x16x64_i8(af[3], w3[j], acc[j], 0, 0, 0);

    // in-reg dequant (static idx) + select this lane's kk pair {2L, 2L+1}
    float d0 = (float)acc[0][0] * s8j[0], d1 = (float)acc[1][0] * s8j[1];
    float d2 = (float)acc[2][0] * s8j[2], d3 = (float)acc[3][0] * s8j[3];
    float d4 = (float)acc[4][0] * s8j[4], d5 = (float)acc[5][0] * s8j[5];
    float d6 = (float)acc[6][0] * s8j[6], d7 = (float)acc[7][0] * s8j[7];
    float v0 = lg == 0 ? d0 : lg == 1 ? d2 : lg == 2 ? d4 : d6;
    float v1 = lg == 0 ? d1 : lg == 1 ? d3 : lg == 2 ? d5 : d7;

    // theta = theta_x + theta_h; cos; pair product
    float c0 = __cosf(u2f(tx << 16) + v0);
    float c1 = __cosf(u2f(tx & 0xffff0000u) + v1);
    float pair = c0 * c1;

    // width-64 inclusive scan of pair products
    float incl = pair;
#pragma unroll
    for (int d = 1; d < 64; d <<= 1) {
      float o = __shfl_up(incl, d);
      if (lane >= d) incl *= o;
    }
    float prefix = __shfl_up(incl, 1);
    if (lane == 0) prefix = 1.f;
    if (hh == 0 && lane == 63) halfTot[g] = incl;
    __syncthreads();                    // B_half
    if (hh) prefix *= halfTot[g];

    // activation + ACT write (1 conflict-free b32/lane)
    float r0v = prefix * c0;
    float a0 = isg ? fast_tanh(r0v * invt) : fast_sigmoid(r0v * invt);
    float r1v = r0v * c1;
    float a1 = isg ? fast_tanh(r1v * invt) : fast_sigmoid(r1v * invt);
    uint pk = (uint)(ushort)f2bf(a0) | ((uint)(ushort)f2bf(a1) << 16);
    *(uint*)&ACT[g * 264 + hh * 128 + lane * 2] = pk;
    __syncthreads();                    // B_act

    // update: thread (e, ukk); both e compute, e==0 does global I/O
    {
      float fv = bf2fu(ACT[0 * 264 + ukk]);
      float iv = bf2fu(ACT[1 * 264 + ukk]);
      float gv = bf2fu(ACT[2 * 264 + ukk]);
      float ov = bf2fu(ACT[3 * 264 + ukk]);
      float cn = fv * creg + iv * gv;
      creg = cn;
      float h = ov * fast_tanh(cn);
      int hq = __float2int_rn(h * 127.f);
      const int r0 = e * 4, r1 = e * 4 + 8;
      A[r0 * 256 + (ukk ^ ((r0 & 7) << 4))] = (signed char)hq;
      A[r1 * 256 + (ukk ^ ((r1 & 7) << 4))] = (signed char)hq;
      if (e == 0) {
        out[((size_t)t * BATCH + row) * DHID + ukk] = h;
        if (t == T_STEPS - 1) {
          out[((size_t)T_STEPS * BATCH + row) * DHID + ukk] = h;
          out[((size_t)T_STEPS * BATCH + BATCH + row) * DHID + ukk] = cn;
        }
        if (last) {
          hGq[(size_t)row * 256 + ukk] = (signed char)hq;
          cG[(size_t)row * 256 + ukk] = cn;
        }
      }
    }
    __syncthreads();                    // B_A

    tx = txn;
  }
}

extern "C" void kernel_launch(void* const* d_in, const int* in_sizes, int n_in,
                              void* d_out, int out_size, void* d_ws, size_t ws_size,
                              hipStream_t stream) {
  (void)in_sizes; (void)n_in; (void)out_size;
  const float* x   = (const float*)d_in[0];
  const float* Wf  = (const float*)d_in[1];
  const float* bf_ = (const float*)d_in[2];
  const float* tf_ = (const float*)d_in[3];
  const float* Wi  = (const float*)d_in[4];
  const float* bi_ = (const float*)d_in[5];
  const float* ti_ = (const float*)d_in[6];
  const float* Wg  = (const float*)d_in[7];
  const float* bg_ = (const float*)d_in[8];
  const float* tg_ = (const float*)d_in[9];
  const float* Wo  = (const float*)d_in[10];
  const float* bo_ = (const float*)d_in[11];
  const float* to_ = (const float*)d_in[12];

  char* ws = (char*)d_ws;
  bf16_t*      Wxp   = (bf16_t*)(ws + WS_WXP);
  signed char* Whq   = (signed char*)(ws + WS_WHQ);
  float*       sw    = (float*)(ws + WS_SW);
  float*       rq    = (float*)(ws + WS_RQ);
  float*       bias  = (float*)(ws + WS_BIAS);
  float*       temps = (float*)(ws + WS_TMP);
  signed char* hGq   = (signed char*)(ws + WS_HGQ);
  float*       cG    = (float*)(ws + WS_CG);
  ushort*      thxH  = (ushort*)(ws + WS_THX);

  size_t avail = ws_size > (size_t)(2u << 20) ? ws_size - (size_t)(2u << 20) : 0;
  int CH = 4;
  const int cands[6] = {128, 64, 32, 16, 8, 4};
  for (int ci = 0; ci < 6; ++ci)
    if ((size_t)cands[ci] * 512 * 1024 <= avail) { CH = cands[ci]; break; }

  hipLaunchKernelGGL(k_scales, dim3(4), dim3(256), 0, stream,
                     Wf, Wi, Wg, Wo, sw, rq);
  hipLaunchKernelGGL(k_packx, dim3(128), dim3(256), 0, stream,
                     Wf, Wi, Wg, Wo, bf_, bi_, bg_, bo_, tf_, ti_, tg_, to_,
                     Wxp, bias, temps);
  hipLaunchKernelGGL(k_packh, dim3(64), dim3(256), 0, stream,
                     Wf, Wi, Wg, Wo, rq, Whq);

  for (int c0 = 0; c0 < T_STEPS; c0 += CH) {
    hipLaunchKernelGGL(gemm_thx, dim3(CH * 4), dim3(256), 0, stream,
                       x + (size_t)c0 * BATCH * DIN, Wxp, bias, thxH);
    hipLaunchKernelGGL(qlstm_rec, dim3(NWG), dim3(NTHREADS), 0, stream,
                       (const uint*)thxH, (const int32x4*)Whq, sw, temps,
                       hGq, cG, (float*)d_out, c0, CH);
  }
}